// Round 6
// baseline (284.034 us; speedup 1.0000x reference)
//
#include <hip/hip_runtime.h>
#include <math.h>

typedef unsigned short u16;
typedef __bf16 bf16x8 __attribute__((ext_vector_type(8)));
typedef float floatx4 __attribute__((ext_vector_type(4)));
typedef float floatx16 __attribute__((ext_vector_type(16)));

#define MFMA16(a, b, c) __builtin_amdgcn_mfma_f32_16x16x32_bf16((a), (b), (c), 0, 0, 0)
#define MFMA32(a, b, c) __builtin_amdgcn_mfma_f32_32x32x16_bf16((a), (b), (c), 0, 0, 0)

__device__ __forceinline__ float bf2f(u16 u) {
  union { float f; unsigned int i; } v; v.i = ((unsigned int)u) << 16; return v.f;
}
__device__ __forceinline__ u16 f2bf(float f) {  // native RNE cvt
  __bf16 h = (__bf16)f;
  union { __bf16 h; u16 u; } v; v.h = h; return v.u;
}
__device__ __forceinline__ bf16x8 cvt8(float4 a, float4 b) {
  bf16x8 r;
  r[0] = (__bf16)a.x; r[1] = (__bf16)a.y; r[2] = (__bf16)a.z; r[3] = (__bf16)a.w;
  r[4] = (__bf16)b.x; r[5] = (__bf16)b.y; r[6] = (__bf16)b.z; r[7] = (__bf16)b.w;
  return r;
}
// Async global->LDS, 16 B per lane. LDS dest = wave-uniform base + lane*16.
__device__ __forceinline__ void gl2lds16(const void* g, void* l) {
  __builtin_amdgcn_global_load_lds(
      (const __attribute__((address_space(1))) unsigned int*)g,
      (__attribute__((address_space(3))) unsigned int*)l, 16, 0, 0);
}

struct GemmArgs {
  const void* A[3];     // fp32 (ABF16=0) or bf16 (ABF16=1) [.,1024]
  const float* W[3];    // fp32 [1024,1024] used as B^T (NT)
  const float* bias[3]; // fp32 [1024]
  void* C[3];
  int out_mode[3];      // 0 = bf16, 1 = bf16 Vt[b,h,d,s], 2 = fp32
};

// C[4096,1024] = A @ W^T + bias, BMx128 tile, BK=32, fp32 acc.
// R5: double-buffered staging (1 barrier/k-step, prefetch overlaps compute —
// attn-v5-proven pattern) + XCD-chunked block swizzle (each XCD owns a
// contiguous x-major band -> A-panels fetched by ~1 XCD, W reused in-band).
template <int BM, int ABF16>
__global__ __launch_bounds__(256) void gemm_nt(GemmArgs args) {
  const int N = 1024, K = 1024;

  // XCD-chunked swizzle. Requires gridDim.x == 8 and total blocks % 8 == 0.
  // HW round-robins dispatch id across 8 XCDs; remap so XCD r gets newids
  // [r*chunk, (r+1)*chunk) = contiguous x-major band.
  const int NY = gridDim.y;
  const int lin = blockIdx.x + (blockIdx.y << 3) + blockIdx.z * (NY << 3);
  const int chunk = NY * gridDim.z;  // total/8
  const int nid = (lin & 7) * chunk + (lin >> 3);
  const int z = nid / (NY << 3);
  const int rem = nid - z * (NY << 3);
  const int m0 = (rem >> 3) * BM, n0 = (rem & 7) * 128;

  const float* W = args.W[z];
  const float* bias = args.bias[z];
  const int out_mode = args.out_mode[z];
  constexpr int MI = BM / 32;

  __shared__ __align__(16) char AsB[2][ABF16 ? BM * 64 : BM * 128];
  __shared__ __align__(16) char BsB[2][128 * 128];

  const int t = threadIdx.x;
  const int wave = t >> 6, lane = t & 63;
  const int lr = lane & 15, quad = lane >> 4;
  const int wm = (wave >> 1) * (BM / 2), wn = (wave & 1) * 64;

  auto stage = [&](int kt, int bi) {
    if constexpr (ABF16) {
      const u16* Ab = (const u16*)args.A[z];
#pragma unroll
      for (int j = 0; j < BM / 64; j++) {
        const int r0 = wave * (BM / 4) + j * 16;
        const int row = r0 + (lane >> 2);
        const int cg = (lane & 3) ^ ((lane >> 2) & 3);
        gl2lds16(Ab + (size_t)(m0 + row) * K + kt + cg * 8, AsB[bi] + r0 * 64 + lane * 16);
      }
    } else {
      const float* Af = (const float*)args.A[z];
#pragma unroll
      for (int j = 0; j < BM / 32; j++) {
        const int r0 = wave * (BM / 4) + j * 8;
        const int row = r0 + (lane >> 3);
        const int cg = (lane & 7) ^ ((lane >> 3) & 7);
        gl2lds16(Af + (size_t)(m0 + row) * K + kt + cg * 4, AsB[bi] + r0 * 128 + lane * 16);
      }
    }
#pragma unroll
    for (int j = 0; j < 4; j++) {
      const int r0 = wave * 32 + j * 8;
      const int row = r0 + (lane >> 3);
      const int cg = (lane & 7) ^ ((lane >> 3) & 7);
      gl2lds16(W + (size_t)(n0 + row) * K + kt + cg * 4, BsB[bi] + r0 * 128 + lane * 16);
    }
  };

  floatx4 acc[MI][4] = {};

  stage(0, 0);
  int buf = 0;
  for (int kt = 0; kt < K; kt += 32) {
    __syncthreads();  // drains vmcnt(0): stage(cur) landed; prev-buf reads done
    if (kt + 32 < K) stage(kt + 32, buf ^ 1);  // prefetch overlaps compute

    bf16x8 af[MI], bf[4];
#pragma unroll
    for (int i = 0; i < MI; i++) {
      const int row = wm + i * 16 + lr;
      if constexpr (ABF16) {
        const int cp = quad ^ (row & 3);
        af[i] = *reinterpret_cast<const bf16x8*>(AsB[buf] + row * 64 + cp * 16);
      } else {
        const int e = row & 7;
        const float4 c0 = *reinterpret_cast<const float4*>(AsB[buf] + row * 128 + ((2 * quad) ^ e) * 16);
        const float4 c1 = *reinterpret_cast<const float4*>(AsB[buf] + row * 128 + ((2 * quad + 1) ^ e) * 16);
        af[i] = cvt8(c0, c1);
      }
    }
#pragma unroll
    for (int i = 0; i < 4; i++) {
      const int row = wn + i * 16 + lr;
      const int e = row & 7;
      const float4 c0 = *reinterpret_cast<const float4*>(BsB[buf] + row * 128 + ((2 * quad) ^ e) * 16);
      const float4 c1 = *reinterpret_cast<const float4*>(BsB[buf] + row * 128 + ((2 * quad + 1) ^ e) * 16);
      bf[i] = cvt8(c0, c1);
    }
#pragma unroll
    for (int mi = 0; mi < MI; mi++)
#pragma unroll
      for (int nf = 0; nf < 4; nf++)
        acc[mi][nf] = MFMA16(af[mi], bf[nf], acc[mi][nf]);
    buf ^= 1;
  }

  // epilogue: C-frag col = lane&15, row = quad*4 + reg
#pragma unroll
  for (int nf = 0; nf < 4; nf++) {
    const int col = n0 + wn + nf * 16 + lr;
    const float bv = bias[col];
#pragma unroll
    for (int mi = 0; mi < MI; mi++) {
      const int row0 = m0 + wm + mi * 16 + quad * 4;
      if (out_mode == 0) {
        u16* C = (u16*)args.C[z];
#pragma unroll
        for (int r = 0; r < 4; r++)
          C[(row0 + r) * N + col] = f2bf(acc[mi][nf][r] + bv);
      } else if (out_mode == 1) {
        u16* C = (u16*)args.C[z];
        const int h = col >> 6, d = col & 63;
        const int b = row0 >> 11, s = row0 & 2047;
        ushort4 pk;
        pk.x = f2bf(acc[mi][nf][0] + bv);
        pk.y = f2bf(acc[mi][nf][1] + bv);
        pk.z = f2bf(acc[mi][nf][2] + bv);
        pk.w = f2bf(acc[mi][nf][3] + bv);
        *reinterpret_cast<ushort4*>(&C[((b * 16 + h) * 64 + d) * 2048 + s]) = pk;
      } else {
        float* C = (float*)args.C[z];
#pragma unroll
        for (int r = 0; r < 4; r++)
          C[(row0 + r) * N + col] = acc[mi][nf][r] + bv;
      }
    }
  }
}

// Interleaved RoPE on Q and K in-place (bf16).
// Q gets scale 0.125*log2(e): folds 1/sqrt(D) AND the exp->exp2 domain switch
// used by the in-register softmax in attn_kernel.
__global__ __launch_bounds__(256) void rope_kernel(u16* Q, u16* Kb) {
  const int idx = blockIdx.x * 256 + threadIdx.x;
  const int tensor = idx >> 19;
  const int i = idx & 524287;
  u16* P = tensor ? Kb : Q;
  const int row = i >> 7;
  const int cg = i & 127;
  const int s = row & 2047;
  const int col0 = cg * 8;
  const float scale = tensor ? 1.0f : 0.18033688011112042f;  // 0.125 * log2(e)
  union { uint4 u; u16 h[8]; } v;
  v.u = *reinterpret_cast<const uint4*>(&P[row * 1024 + col0]);
  const int j0 = (col0 & 63) >> 1;
#pragma unroll
  for (int p = 0; p < 4; p++) {
    const int j = j0 + p;
    const float inv = exp2f(-(float)j * (13.287712379549449f / 32.0f));  // 10000^(-j/32)
    const float f = (float)s * inv;
    float sn, cs;
    sincosf(f, &sn, &cs);
    const float e = bf2f(v.h[2 * p]), o = bf2f(v.h[2 * p + 1]);
    v.h[2 * p]     = f2bf((e * cs - o * sn) * scale);
    v.h[2 * p + 1] = f2bf((o * cs + e * sn) * scale);
  }
  *reinterpret_cast<uint4*>(&P[row * 1024 + col0]) = v.u;
}

// P^T fragment build: regs g..g+7 of a 32-reg S^T acc hold
// k = base + (r&3) + 8*(r>>2) + 4*hi (hi = lane>>5), q = lane&31.
// B-operand of mfma32 needs lane to hold k = base + 8*hi + j (j=0..7).
// cvt_pk pairs + v_permlane32_swap_b32 (dst' = [dst.lo, src.lo],
// src' = [dst.hi, src.hi]; partner lane l^32 has the SAME q) produce exactly
// that: wA'=j{0,1}, wC'=j{2,3}, wB'=j{4,5}, wD'=j{6,7}.
#define MAKE_PB(pp, g, out) do {                                              \
    unsigned int wA, wB, wC, wD;                                              \
    asm("v_cvt_pk_bf16_f32 %0, %1, %2" : "=v"(wA) : "v"((pp)[(g)+0]), "v"((pp)[(g)+1])); \
    asm("v_cvt_pk_bf16_f32 %0, %1, %2" : "=v"(wB) : "v"((pp)[(g)+4]), "v"((pp)[(g)+5])); \
    asm("v_cvt_pk_bf16_f32 %0, %1, %2" : "=v"(wC) : "v"((pp)[(g)+2]), "v"((pp)[(g)+3])); \
    asm("v_cvt_pk_bf16_f32 %0, %1, %2" : "=v"(wD) : "v"((pp)[(g)+6]), "v"((pp)[(g)+7])); \
    asm("v_permlane32_swap_b32 %0, %1" : "+v"(wA), "+v"(wB));                 \
    asm("v_permlane32_swap_b32 %0, %1" : "+v"(wC), "+v"(wD));                 \
    union { unsigned int w[4]; bf16x8 v; } u_;                                \
    u_.w[0] = wA; u_.w[1] = wC; u_.w[2] = wB; u_.w[3] = wD;                   \
    (out) = u_.v;                                                             \
  } while (0)

// Flash attention v6 (R5): v5 + XCD-chunked swizzle (KV panels per (b,h)
// now fetched by ~1 XCD instead of 8). Structure unchanged from v5.
__global__ __launch_bounds__(256, 2) void attn_kernel(const u16* Q, const u16* K,
                                                      const u16* Vt, u16* O) {
  // grid (16,32) = 512 blocks; chunk = 64/XCD -> 4 consecutive bh per XCD.
  const int lin = blockIdx.x + (blockIdx.y << 4);
  const int nid = (lin & 7) * 64 + (lin >> 3);
  const int bx = nid & 15, bh = nid >> 4;

  const int b = bh >> 4, h = bh & 15;
  const int t = threadIdx.x;
  const int warp = t >> 6, lane = t & 63;
  const int lq = lane & 31, hi = lane >> 5;

  __shared__ __align__(16) u16 Ks[2][64][64];
  __shared__ __align__(16) u16 Vs[2][64][64];

  const int q0 = bx * 128 + warp * 32;

  // Q B-frag: qf[s][j] = Q[q0+lq][h*64 + 16s + 8hi + j]
  const u16* qp = &Q[(size_t)(b * 2048 + q0 + lq) * 1024 + h * 64 + hi * 8];
  bf16x8 qf[4];
#pragma unroll
  for (int s = 0; s < 4; s++) qf[s] = *reinterpret_cast<const bf16x8*>(&qp[s * 16]);

  const u16* kbase = &K[(size_t)b * 2048 * 1024 + h * 64];
  const u16* vbase = &Vt[(size_t)bh * 131072];

  // Staging: lane l writes LDS granule (l&7) of row base+(l>>3); source
  // granule pre-swizzled (l&7)^(l>>3) => LDS granule g of row r holds
  // logical granule g^(r&7). Each warp stages 16 K-rows + 16 V-rows.
  const int srr = lane >> 3;            // 0..7 == dest row & 7
  const int scg = (lane & 7) ^ srr;     // swizzled source granule

  auto stage = [&](int kt2, int bufi) {
#pragma unroll
    for (int j = 0; j < 2; j++) {
      const int r0 = warp * 16 + j * 8;
      const int row = r0 + srr;
      gl2lds16(kbase + (size_t)(kt2 + row) * 1024 + scg * 8, &Ks[bufi][r0][0]);
      gl2lds16(vbase + (size_t)row * 2048 + kt2 + scg * 8, &Vs[bufi][r0][0]);
    }
  };

  floatx16 o0 = {}, o1 = {};
  float m = -1.0e30f, l = 0.0f;

  stage(0, 0);
  int buf = 0;
  for (int kt = 0; kt < 2048; kt += 64) {
    __syncthreads();  // drains vmcnt(0): stage(cur) done; prev-buf reads done
    if (kt + 64 < 2048) stage(kt + 64, buf ^ 1);  // async prefetch overlaps compute

    // K A-frag: kf[kb][s][j] = K[kt+32kb+lq][h*64+16s+8hi+j]
    bf16x8 kf[2][4], vf[4][2];
#pragma unroll
    for (int kb = 0; kb < 2; kb++) {
      const int r = kb * 32 + lq;
#pragma unroll
      for (int s = 0; s < 4; s++)
        kf[kb][s] = *reinterpret_cast<const bf16x8*>(&Ks[buf][r][((s * 2 + hi) ^ (r & 7)) * 8]);
    }
    // Vt A-frag: vf[ks][d][j] = Vt[32d+lq][kt+16ks+8hi+j]
#pragma unroll
    for (int d = 0; d < 2; d++) {
      const int r = d * 32 + lq;
#pragma unroll
      for (int ks = 0; ks < 4; ks++)
        vf[ks][d] = *reinterpret_cast<const bf16x8*>(&Vs[buf][r][((ks * 2 + hi) ^ (r & 7)) * 8]);
    }

    // QK^T: p0/p1 reg r = S^T[k = kt + 32kb + (r&3)+8*(r>>2)+4hi][q0+lq]
    floatx16 p0 = {}, p1 = {};
#pragma unroll
    for (int s = 0; s < 4; s++) {
      p0 = MFMA32(kf[0][s], qf[s], p0);
      p1 = MFMA32(kf[1][s], qf[s], p1);
    }

    // online softmax (log2 domain), q = lq lane-local; partner l^32 has other 32 k
    float mx = p0[0];
#pragma unroll
    for (int r = 1; r < 16; r++) mx = fmaxf(mx, p0[r]);
#pragma unroll
    for (int r = 0; r < 16; r++) mx = fmaxf(mx, p1[r]);
    mx = fmaxf(mx, __shfl_xor(mx, 32, 64));
    if (!__all(mx <= m + 10.0f)) {  // defer-max: P bounded by 2^10
      const float mn = fmaxf(m, mx);
      const float al = __builtin_amdgcn_exp2f(m - mn);
      m = mn;
      l *= al;
#pragma unroll
      for (int r = 0; r < 16; r++) { o0[r] *= al; o1[r] *= al; }
    }
    float sum = 0.0f;
#pragma unroll
    for (int r = 0; r < 16; r++) { p0[r] = __builtin_amdgcn_exp2f(p0[r] - m); sum += p0[r]; }
#pragma unroll
    for (int r = 0; r < 16; r++) { p1[r] = __builtin_amdgcn_exp2f(p1[r] - m); sum += p1[r]; }
    l += sum + __shfl_xor(sum, 32, 64);

    // P^T -> bf16 B-frags (in-register)
    bf16x8 pb0, pb1, pb2, pb3;
    MAKE_PB(p0, 0, pb0);
    MAKE_PB(p0, 8, pb1);
    MAKE_PB(p1, 0, pb2);
    MAKE_PB(p1, 8, pb3);

    // PV: O^T += Vt @ P^T
    o0 = MFMA32(vf[0][0], pb0, o0);
    o1 = MFMA32(vf[0][1], pb0, o1);
    o0 = MFMA32(vf[1][0], pb1, o0);
    o1 = MFMA32(vf[1][1], pb1, o1);
    o0 = MFMA32(vf[2][0], pb2, o0);
    o1 = MFMA32(vf[2][1], pb2, o1);
    o0 = MFMA32(vf[3][0], pb3, o0);
    o1 = MFMA32(vf[3][1], pb3, o1);

    buf ^= 1;
  }

  // epilogue: O^T reg r -> d = (r&3) + 8*(r>>2) + 4hi + 32*dblk, q = q0+lq
  const float rl = 1.0f / l;
  u16* op = &O[(size_t)(b * 2048 + q0 + lq) * 1024 + h * 64 + hi * 4];
#pragma unroll
  for (int rq = 0; rq < 4; rq++) {
    ushort4 s0, s1;
    s0.x = f2bf(o0[4 * rq + 0] * rl); s0.y = f2bf(o0[4 * rq + 1] * rl);
    s0.z = f2bf(o0[4 * rq + 2] * rl); s0.w = f2bf(o0[4 * rq + 3] * rl);
    s1.x = f2bf(o1[4 * rq + 0] * rl); s1.y = f2bf(o1[4 * rq + 1] * rl);
    s1.z = f2bf(o1[4 * rq + 2] * rl); s1.w = f2bf(o1[4 * rq + 3] * rl);
    *reinterpret_cast<ushort4*>(&op[rq * 8]) = s0;
    *reinterpret_cast<ushort4*>(&op[rq * 8 + 32]) = s1;
  }
}

extern "C" void kernel_launch(void* const* d_in, const int* in_sizes, int n_in,
                              void* d_out, int out_size, void* d_ws, size_t ws_size,
                              hipStream_t stream) {
  (void)in_sizes; (void)n_in; (void)out_size; (void)ws_size;
  const float* query = (const float*)d_in[0];
  const float* key   = (const float*)d_in[1];
  const float* value = (const float*)d_in[2];
  const float* Wq = (const float*)d_in[3];
  const float* bq = (const float*)d_in[4];
  const float* Wk = (const float*)d_in[5];
  const float* bk = (const float*)d_in[6];
  const float* Wv = (const float*)d_in[7];
  const float* bv = (const float*)d_in[8];
  const float* Wo = (const float*)d_in[9];
  const float* bo = (const float*)d_in[10];

  // Qb (8 MB bf16) in ws; Kb + Vt (16 MB bf16) inside d_out (16 MB fp32),
  // dead until the final fp32 GEMM overwrites it.
  u16* Qb = (u16*)d_ws;
  u16* Kb = (u16*)d_out;
  u16* Vt = (u16*)d_out + 4194304;

  GemmArgs g1;
  g1.A[0] = query; g1.W[0] = Wq; g1.bias[0] = bq; g1.C[0] = Qb; g1.out_mode[0] = 0;
  g1.A[1] = key;   g1.W[1] = Wk; g1.bias[1] = bk; g1.C[1] = Kb; g1.out_mode[1] = 0;
  g1.A[2] = value; g1.W[2] = Wv; g1.bias[2] = bv; g1.C[2] = Vt; g1.out_mode[2] = 1;
  gemm_nt<128, 0><<<dim3(8, 32, 3), dim3(256), 0, stream>>>(g1);

  rope_kernel<<<dim3(4096), dim3(256), 0, stream>>>(Qb, Kb);

  attn_kernel<<<dim3(16, 32), dim3(256), 0, stream>>>(Qb, Kb, Vt, Qb);

  // Final projection: bf16 attn output -> fp32 d_out. BM=64 -> 512 blocks.
  GemmArgs g2;
  for (int i = 0; i < 3; i++) {
    g2.A[i] = Qb; g2.W[i] = Wo; g2.bias[i] = bo;
    g2.C[i] = d_out; g2.out_mode[i] = 2;
  }
  gemm_nt<64, 1><<<dim3(8, 64, 1), dim3(256), 0, stream>>>(g2);
}

// Round 7
// 261.882 us; speedup vs baseline: 1.0846x; 1.0846x over previous
//
#include <hip/hip_runtime.h>
#include <math.h>

typedef unsigned short u16;
typedef __bf16 bf16x8 __attribute__((ext_vector_type(8)));
typedef float floatx4 __attribute__((ext_vector_type(4)));
typedef float floatx16 __attribute__((ext_vector_type(16)));

#define MFMA16(a, b, c) __builtin_amdgcn_mfma_f32_16x16x32_bf16((a), (b), (c), 0, 0, 0)
#define MFMA32(a, b, c) __builtin_amdgcn_mfma_f32_32x32x16_bf16((a), (b), (c), 0, 0, 0)

__device__ __forceinline__ float bf2f(u16 u) {
  union { float f; unsigned int i; } v; v.i = ((unsigned int)u) << 16; return v.f;
}
__device__ __forceinline__ u16 f2bf(float f) {  // native RNE cvt
  __bf16 h = (__bf16)f;
  union { __bf16 h; u16 u; } v; v.h = h; return v.u;
}
__device__ __forceinline__ bf16x8 cvt8(float4 a, float4 b) {
  bf16x8 r;
  r[0] = (__bf16)a.x; r[1] = (__bf16)a.y; r[2] = (__bf16)a.z; r[3] = (__bf16)a.w;
  r[4] = (__bf16)b.x; r[5] = (__bf16)b.y; r[6] = (__bf16)b.z; r[7] = (__bf16)b.w;
  return r;
}
// Async global->LDS, 16 B per lane. LDS dest = wave-uniform base + lane*16.
__device__ __forceinline__ void gl2lds16(const void* g, void* l) {
  __builtin_amdgcn_global_load_lds(
      (const __attribute__((address_space(1))) unsigned int*)g,
      (__attribute__((address_space(3))) unsigned int*)l, 16, 0, 0);
}

struct GemmArgs {
  const void* A[3];     // fp32 (ABF16=0) or bf16 (ABF16=1) [.,1024]
  const float* W[3];    // fp32 [1024,1024] used as B^T (NT)
  const float* bias[3]; // fp32 [1024]
  void* C[3];
  int out_mode[3];      // 0 = bf16, 1 = bf16 Vt[b,h,d,s], 2 = fp32
};

// C[.,1024] = A @ W^T + bias, BMx128 tile, BK=32, fp32 acc.
// R6: double-buffered staging (1 barrier/k-step) + XCD-chunked swizzle
// (R6-proven: FETCH 206->59.6 MB = ideal). R7 fix: smaller BM to restore
// occupancy lost to the doubled LDS (R6: 64 KB -> 2 blocks/CU -> 105 us).
// QKV BM=64: LDS 48 KB -> 3 blocks/CU exact; proj BM=32: 36 KB -> 4/CU exact.
template <int BM, int ABF16>
__global__ __launch_bounds__(256) void gemm_nt(GemmArgs args) {
  const int N = 1024, K = 1024;

  // XCD-chunked swizzle. Requires gridDim.x == 8 and total blocks % 8 == 0.
  const int NY = gridDim.y;
  const int lin = blockIdx.x + (blockIdx.y << 3) + blockIdx.z * (NY << 3);
  const int chunk = NY * gridDim.z;  // total/8
  const int nid = (lin & 7) * chunk + (lin >> 3);
  const int z = nid / (NY << 3);
  const int rem = nid - z * (NY << 3);
  const int m0 = (rem >> 3) * BM, n0 = (rem & 7) * 128;

  const float* W = args.W[z];
  const float* bias = args.bias[z];
  const int out_mode = args.out_mode[z];
  constexpr int MI = BM / 32;

  __shared__ __align__(16) char AsB[2][ABF16 ? BM * 64 : BM * 128];
  __shared__ __align__(16) char BsB[2][128 * 128];

  const int t = threadIdx.x;
  const int wave = t >> 6, lane = t & 63;
  const int lr = lane & 15, quad = lane >> 4;
  const int wm = (wave >> 1) * (BM / 2), wn = (wave & 1) * 64;

  auto stage = [&](int kt, int bi) {
    if constexpr (ABF16) {
      const u16* Ab = (const u16*)args.A[z];
      constexpr int NI = BM / 16;  // total 1KB wave-instrs for the A tile
#pragma unroll
      for (int j = 0; j < (NI + 3) / 4; j++) {
        const int ii = wave + j * 4;
        if (NI >= 4 || ii < NI) {  // wave-uniform guard
          const int r0 = ii * 16;
          const int row = r0 + (lane >> 2);
          const int cg = (lane & 3) ^ ((lane >> 2) & 3);
          gl2lds16(Ab + (size_t)(m0 + row) * K + kt + cg * 8, AsB[bi] + r0 * 64 + lane * 16);
        }
      }
    } else {
      const float* Af = (const float*)args.A[z];
#pragma unroll
      for (int j = 0; j < BM / 32; j++) {
        const int r0 = wave * (BM / 4) + j * 8;
        const int row = r0 + (lane >> 3);
        const int cg = (lane & 7) ^ ((lane >> 3) & 7);
        gl2lds16(Af + (size_t)(m0 + row) * K + kt + cg * 4, AsB[bi] + r0 * 128 + lane * 16);
      }
    }
#pragma unroll
    for (int j = 0; j < 4; j++) {
      const int r0 = wave * 32 + j * 8;
      const int row = r0 + (lane >> 3);
      const int cg = (lane & 7) ^ ((lane >> 3) & 7);
      gl2lds16(W + (size_t)(n0 + row) * K + kt + cg * 4, BsB[bi] + r0 * 128 + lane * 16);
    }
  };

  floatx4 acc[MI][4] = {};

  stage(0, 0);
  int buf = 0;
  for (int kt = 0; kt < K; kt += 32) {
    __syncthreads();  // drains vmcnt(0): stage(cur) landed; prev-buf reads done
    if (kt + 32 < K) stage(kt + 32, buf ^ 1);  // prefetch overlaps compute

    bf16x8 af[MI], bf[4];
#pragma unroll
    for (int i = 0; i < MI; i++) {
      const int row = wm + i * 16 + lr;
      if constexpr (ABF16) {
        const int cp = quad ^ (row & 3);
        af[i] = *reinterpret_cast<const bf16x8*>(AsB[buf] + row * 64 + cp * 16);
      } else {
        const int e = row & 7;
        const float4 c0 = *reinterpret_cast<const float4*>(AsB[buf] + row * 128 + ((2 * quad) ^ e) * 16);
        const float4 c1 = *reinterpret_cast<const float4*>(AsB[buf] + row * 128 + ((2 * quad + 1) ^ e) * 16);
        af[i] = cvt8(c0, c1);
      }
    }
#pragma unroll
    for (int i = 0; i < 4; i++) {
      const int row = wn + i * 16 + lr;
      const int e = row & 7;
      const float4 c0 = *reinterpret_cast<const float4*>(BsB[buf] + row * 128 + ((2 * quad) ^ e) * 16);
      const float4 c1 = *reinterpret_cast<const float4*>(BsB[buf] + row * 128 + ((2 * quad + 1) ^ e) * 16);
      bf[i] = cvt8(c0, c1);
    }
#pragma unroll
    for (int mi = 0; mi < MI; mi++)
#pragma unroll
      for (int nf = 0; nf < 4; nf++)
        acc[mi][nf] = MFMA16(af[mi], bf[nf], acc[mi][nf]);
    buf ^= 1;
  }

  // epilogue: C-frag col = lane&15, row = quad*4 + reg
#pragma unroll
  for (int nf = 0; nf < 4; nf++) {
    const int col = n0 + wn + nf * 16 + lr;
    const float bv = bias[col];
#pragma unroll
    for (int mi = 0; mi < MI; mi++) {
      const int row0 = m0 + wm + mi * 16 + quad * 4;
      if (out_mode == 0) {
        u16* C = (u16*)args.C[z];
#pragma unroll
        for (int r = 0; r < 4; r++)
          C[(row0 + r) * N + col] = f2bf(acc[mi][nf][r] + bv);
      } else if (out_mode == 1) {
        u16* C = (u16*)args.C[z];
        const int h = col >> 6, d = col & 63;
        const int b = row0 >> 11, s = row0 & 2047;
        ushort4 pk;
        pk.x = f2bf(acc[mi][nf][0] + bv);
        pk.y = f2bf(acc[mi][nf][1] + bv);
        pk.z = f2bf(acc[mi][nf][2] + bv);
        pk.w = f2bf(acc[mi][nf][3] + bv);
        *reinterpret_cast<ushort4*>(&C[((b * 16 + h) * 64 + d) * 2048 + s]) = pk;
      } else {
        float* C = (float*)args.C[z];
#pragma unroll
        for (int r = 0; r < 4; r++)
          C[(row0 + r) * N + col] = acc[mi][nf][r] + bv;
      }
    }
  }
}

// Interleaved RoPE on Q and K in-place (bf16).
// Q gets scale 0.125*log2(e): folds 1/sqrt(D) AND the exp->exp2 domain switch
// used by the in-register softmax in attn_kernel.
__global__ __launch_bounds__(256) void rope_kernel(u16* Q, u16* Kb) {
  const int idx = blockIdx.x * 256 + threadIdx.x;
  const int tensor = idx >> 19;
  const int i = idx & 524287;
  u16* P = tensor ? Kb : Q;
  const int row = i >> 7;
  const int cg = i & 127;
  const int s = row & 2047;
  const int col0 = cg * 8;
  const float scale = tensor ? 1.0f : 0.18033688011112042f;  // 0.125 * log2(e)
  union { uint4 u; u16 h[8]; } v;
  v.u = *reinterpret_cast<const uint4*>(&P[row * 1024 + col0]);
  const int j0 = (col0 & 63) >> 1;
#pragma unroll
  for (int p = 0; p < 4; p++) {
    const int j = j0 + p;
    const float inv = exp2f(-(float)j * (13.287712379549449f / 32.0f));  // 10000^(-j/32)
    const float f = (float)s * inv;
    float sn, cs;
    sincosf(f, &sn, &cs);
    const float e = bf2f(v.h[2 * p]), o = bf2f(v.h[2 * p + 1]);
    v.h[2 * p]     = f2bf((e * cs - o * sn) * scale);
    v.h[2 * p + 1] = f2bf((o * cs + e * sn) * scale);
  }
  *reinterpret_cast<uint4*>(&P[row * 1024 + col0]) = v.u;
}

// P^T fragment build: regs g..g+7 of a 32-reg S^T acc hold
// k = base + (r&3) + 8*(r>>2) + 4*hi (hi = lane>>5), q = lane&31.
// B-operand of mfma32 needs lane to hold k = base + 8*hi + j (j=0..7).
// cvt_pk pairs + v_permlane32_swap_b32 (dst' = [dst.lo, src.lo],
// src' = [dst.hi, src.hi]; partner lane l^32 has the SAME q) produce exactly
// that: wA'=j{0,1}, wC'=j{2,3}, wB'=j{4,5}, wD'=j{6,7}.
#define MAKE_PB(pp, g, out) do {                                              \
    unsigned int wA, wB, wC, wD;                                              \
    asm("v_cvt_pk_bf16_f32 %0, %1, %2" : "=v"(wA) : "v"((pp)[(g)+0]), "v"((pp)[(g)+1])); \
    asm("v_cvt_pk_bf16_f32 %0, %1, %2" : "=v"(wB) : "v"((pp)[(g)+4]), "v"((pp)[(g)+5])); \
    asm("v_cvt_pk_bf16_f32 %0, %1, %2" : "=v"(wC) : "v"((pp)[(g)+2]), "v"((pp)[(g)+3])); \
    asm("v_cvt_pk_bf16_f32 %0, %1, %2" : "=v"(wD) : "v"((pp)[(g)+6]), "v"((pp)[(g)+7])); \
    asm("v_permlane32_swap_b32 %0, %1" : "+v"(wA), "+v"(wB));                 \
    asm("v_permlane32_swap_b32 %0, %1" : "+v"(wC), "+v"(wD));                 \
    union { unsigned int w[4]; bf16x8 v; } u_;                                \
    u_.w[0] = wA; u_.w[1] = wC; u_.w[2] = wB; u_.w[3] = wD;                   \
    (out) = u_.v;                                                             \
  } while (0)

// Flash attention v6 (R5/R6-proven): swapped-operand in-register compute +
// coalesced double-buffered LDS staging + XCD-chunked swizzle. Unchanged.
__global__ __launch_bounds__(256, 2) void attn_kernel(const u16* Q, const u16* K,
                                                      const u16* Vt, u16* O) {
  // grid (16,32) = 512 blocks; chunk = 64/XCD -> 4 consecutive bh per XCD.
  const int lin = blockIdx.x + (blockIdx.y << 4);
  const int nid = (lin & 7) * 64 + (lin >> 3);
  const int bx = nid & 15, bh = nid >> 4;

  const int b = bh >> 4, h = bh & 15;
  const int t = threadIdx.x;
  const int warp = t >> 6, lane = t & 63;
  const int lq = lane & 31, hi = lane >> 5;

  __shared__ __align__(16) u16 Ks[2][64][64];
  __shared__ __align__(16) u16 Vs[2][64][64];

  const int q0 = bx * 128 + warp * 32;

  // Q B-frag: qf[s][j] = Q[q0+lq][h*64 + 16s + 8hi + j]
  const u16* qp = &Q[(size_t)(b * 2048 + q0 + lq) * 1024 + h * 64 + hi * 8];
  bf16x8 qf[4];
#pragma unroll
  for (int s = 0; s < 4; s++) qf[s] = *reinterpret_cast<const bf16x8*>(&qp[s * 16]);

  const u16* kbase = &K[(size_t)b * 2048 * 1024 + h * 64];
  const u16* vbase = &Vt[(size_t)bh * 131072];

  // Staging: lane l writes LDS granule (l&7) of row base+(l>>3); source
  // granule pre-swizzled (l&7)^(l>>3) => LDS granule g of row r holds
  // logical granule g^(r&7). Each warp stages 16 K-rows + 16 V-rows.
  const int srr = lane >> 3;            // 0..7 == dest row & 7
  const int scg = (lane & 7) ^ srr;     // swizzled source granule

  auto stage = [&](int kt2, int bufi) {
#pragma unroll
    for (int j = 0; j < 2; j++) {
      const int r0 = warp * 16 + j * 8;
      const int row = r0 + srr;
      gl2lds16(kbase + (size_t)(kt2 + row) * 1024 + scg * 8, &Ks[bufi][r0][0]);
      gl2lds16(vbase + (size_t)row * 2048 + kt2 + scg * 8, &Vs[bufi][r0][0]);
    }
  };

  floatx16 o0 = {}, o1 = {};
  float m = -1.0e30f, l = 0.0f;

  stage(0, 0);
  int buf = 0;
  for (int kt = 0; kt < 2048; kt += 64) {
    __syncthreads();  // drains vmcnt(0): stage(cur) done; prev-buf reads done
    if (kt + 64 < 2048) stage(kt + 64, buf ^ 1);  // async prefetch overlaps compute

    // K A-frag: kf[kb][s][j] = K[kt+32kb+lq][h*64+16s+8hi+j]
    bf16x8 kf[2][4], vf[4][2];
#pragma unroll
    for (int kb = 0; kb < 2; kb++) {
      const int r = kb * 32 + lq;
#pragma unroll
      for (int s = 0; s < 4; s++)
        kf[kb][s] = *reinterpret_cast<const bf16x8*>(&Ks[buf][r][((s * 2 + hi) ^ (r & 7)) * 8]);
    }
    // Vt A-frag: vf[ks][d][j] = Vt[32d+lq][kt+16ks+8hi+j]
#pragma unroll
    for (int d = 0; d < 2; d++) {
      const int r = d * 32 + lq;
#pragma unroll
      for (int ks = 0; ks < 4; ks++)
        vf[ks][d] = *reinterpret_cast<const bf16x8*>(&Vs[buf][r][((ks * 2 + hi) ^ (r & 7)) * 8]);
    }

    // QK^T: p0/p1 reg r = S^T[k = kt + 32kb + (r&3)+8*(r>>2)+4hi][q0+lq]
    floatx16 p0 = {}, p1 = {};
#pragma unroll
    for (int s = 0; s < 4; s++) {
      p0 = MFMA32(kf[0][s], qf[s], p0);
      p1 = MFMA32(kf[1][s], qf[s], p1);
    }

    // online softmax (log2 domain), q = lq lane-local; partner l^32 has other 32 k
    float mx = p0[0];
#pragma unroll
    for (int r = 1; r < 16; r++) mx = fmaxf(mx, p0[r]);
#pragma unroll
    for (int r = 0; r < 16; r++) mx = fmaxf(mx, p1[r]);
    mx = fmaxf(mx, __shfl_xor(mx, 32, 64));
    if (!__all(mx <= m + 10.0f)) {  // defer-max: P bounded by 2^10
      const float mn = fmaxf(m, mx);
      const float al = __builtin_amdgcn_exp2f(m - mn);
      m = mn;
      l *= al;
#pragma unroll
      for (int r = 0; r < 16; r++) { o0[r] *= al; o1[r] *= al; }
    }
    float sum = 0.0f;
#pragma unroll
    for (int r = 0; r < 16; r++) { p0[r] = __builtin_amdgcn_exp2f(p0[r] - m); sum += p0[r]; }
#pragma unroll
    for (int r = 0; r < 16; r++) { p1[r] = __builtin_amdgcn_exp2f(p1[r] - m); sum += p1[r]; }
    l += sum + __shfl_xor(sum, 32, 64);

    // P^T -> bf16 B-frags (in-register)
    bf16x8 pb0, pb1, pb2, pb3;
    MAKE_PB(p0, 0, pb0);
    MAKE_PB(p0, 8, pb1);
    MAKE_PB(p1, 0, pb2);
    MAKE_PB(p1, 8, pb3);

    // PV: O^T += Vt @ P^T
    o0 = MFMA32(vf[0][0], pb0, o0);
    o1 = MFMA32(vf[0][1], pb0, o1);
    o0 = MFMA32(vf[1][0], pb1, o0);
    o1 = MFMA32(vf[1][1], pb1, o1);
    o0 = MFMA32(vf[2][0], pb2, o0);
    o1 = MFMA32(vf[2][1], pb2, o1);
    o0 = MFMA32(vf[3][0], pb3, o0);
    o1 = MFMA32(vf[3][1], pb3, o1);

    buf ^= 1;
  }

  // epilogue: O^T reg r -> d = (r&3) + 8*(r>>2) + 4hi + 32*dblk, q = q0+lq
  const float rl = 1.0f / l;
  u16* op = &O[(size_t)(b * 2048 + q0 + lq) * 1024 + h * 64 + hi * 4];
#pragma unroll
  for (int rq = 0; rq < 4; rq++) {
    ushort4 s0, s1;
    s0.x = f2bf(o0[4 * rq + 0] * rl); s0.y = f2bf(o0[4 * rq + 1] * rl);
    s0.z = f2bf(o0[4 * rq + 2] * rl); s0.w = f2bf(o0[4 * rq + 3] * rl);
    s1.x = f2bf(o1[4 * rq + 0] * rl); s1.y = f2bf(o1[4 * rq + 1] * rl);
    s1.z = f2bf(o1[4 * rq + 2] * rl); s1.w = f2bf(o1[4 * rq + 3] * rl);
    *reinterpret_cast<ushort4*>(&op[rq * 8]) = s0;
    *reinterpret_cast<ushort4*>(&op[rq * 8 + 32]) = s1;
  }
}

extern "C" void kernel_launch(void* const* d_in, const int* in_sizes, int n_in,
                              void* d_out, int out_size, void* d_ws, size_t ws_size,
                              hipStream_t stream) {
  (void)in_sizes; (void)n_in; (void)out_size; (void)ws_size;
  const float* query = (const float*)d_in[0];
  const float* key   = (const float*)d_in[1];
  const float* value = (const float*)d_in[2];
  const float* Wq = (const float*)d_in[3];
  const float* bq = (const float*)d_in[4];
  const float* Wk = (const float*)d_in[5];
  const float* bk = (const float*)d_in[6];
  const float* Wv = (const float*)d_in[7];
  const float* bv = (const float*)d_in[8];
  const float* Wo = (const float*)d_in[9];
  const float* bo = (const float*)d_in[10];

  // Qb (8 MB bf16) in ws; Kb + Vt (16 MB bf16) inside d_out (16 MB fp32),
  // dead until the final fp32 GEMM overwrites it.
  u16* Qb = (u16*)d_ws;
  u16* Kb = (u16*)d_out;
  u16* Vt = (u16*)d_out + 4194304;

  GemmArgs g1;
  g1.A[0] = query; g1.W[0] = Wq; g1.bias[0] = bq; g1.C[0] = Qb; g1.out_mode[0] = 0;
  g1.A[1] = key;   g1.W[1] = Wk; g1.bias[1] = bk; g1.C[1] = Kb; g1.out_mode[1] = 0;
  g1.A[2] = value; g1.W[2] = Wv; g1.bias[2] = bv; g1.C[2] = Vt; g1.out_mode[2] = 1;
  // BM=64 -> 1536 blocks, 48 KB LDS -> 3 blocks/CU exact, pipelined.
  gemm_nt<64, 0><<<dim3(8, 64, 3), dim3(256), 0, stream>>>(g1);

  rope_kernel<<<dim3(4096), dim3(256), 0, stream>>>(Qb, Kb);

  attn_kernel<<<dim3(16, 32), dim3(256), 0, stream>>>(Qb, Kb, Vt, Qb);

  // Final projection: bf16 attn output -> fp32 d_out.
  // BM=32 -> 1024 blocks, 36 KB LDS -> 4 blocks/CU exact.
  GemmArgs g2;
  for (int i = 0; i < 3; i++) {
    g2.A[i] = Qb; g2.W[i] = Wo; g2.bias[i] = bo;
    g2.C[i] = d_out; g2.out_mode[i] = 2;
  }
  gemm_nt<32, 1><<<dim3(8, 128, 1), dim3(256), 0, stream>>>(g2);
}

// Round 8
// 231.092 us; speedup vs baseline: 1.2291x; 1.1332x over previous
//
#include <hip/hip_runtime.h>
#include <math.h>

typedef unsigned short u16;
typedef __bf16 bf16x8 __attribute__((ext_vector_type(8)));
typedef float floatx4 __attribute__((ext_vector_type(4)));
typedef float floatx16 __attribute__((ext_vector_type(16)));

#define MFMA16(a, b, c) __builtin_amdgcn_mfma_f32_16x16x32_bf16((a), (b), (c), 0, 0, 0)
#define MFMA32(a, b, c) __builtin_amdgcn_mfma_f32_32x32x16_bf16((a), (b), (c), 0, 0, 0)

__device__ __forceinline__ float bf2f(u16 u) {
  union { float f; unsigned int i; } v; v.i = ((unsigned int)u) << 16; return v.f;
}
__device__ __forceinline__ u16 f2bf(float f) {  // native RNE cvt
  __bf16 h = (__bf16)f;
  union { __bf16 h; u16 u; } v; v.h = h; return v.u;
}
__device__ __forceinline__ bf16x8 cvt8(float4 a, float4 b) {
  bf16x8 r;
  r[0] = (__bf16)a.x; r[1] = (__bf16)a.y; r[2] = (__bf16)a.z; r[3] = (__bf16)a.w;
  r[4] = (__bf16)b.x; r[5] = (__bf16)b.y; r[6] = (__bf16)b.z; r[7] = (__bf16)b.w;
  return r;
}
// Async global->LDS, 16 B per lane. LDS dest = wave-uniform base + lane*16.
__device__ __forceinline__ void gl2lds16(const void* g, void* l) {
  __builtin_amdgcn_global_load_lds(
      (const __attribute__((address_space(1))) unsigned int*)g,
      (__attribute__((address_space(3))) unsigned int*)l, 16, 0, 0);
}

// fp32 -> bf16 elementwise, 8 elems/thread (32B read, 16B write, coalesced).
struct CvtArgs { const float* src[3]; u16* dst[3]; };
__global__ __launch_bounds__(256) void cvt_kernel(CvtArgs a) {
  const float* s = a.src[blockIdx.z];
  u16* d = a.dst[blockIdx.z];
  const int i = (blockIdx.x * 256 + threadIdx.x) * 8;
  const float4 x = *reinterpret_cast<const float4*>(s + i);
  const float4 y = *reinterpret_cast<const float4*>(s + i + 4);
  *reinterpret_cast<bf16x8*>(&d[i]) = cvt8(x, y);
}

struct GemmArgs {
  const void* A[3];     // fp32 (ABF16=0) or bf16 (ABF16=1) [.,1024]
  const void* W[3];     // fp32 (WBF16=0) or bf16 (WBF16=1) [1024,1024], B^T (NT)
  const float* bias[3]; // fp32 [1024]
  void* C[3];
  int out_mode[3];      // 0 = bf16, 1 = bf16 Vt[b,h,d,s], 2 = fp32
};

// C[.,1024] = A @ W^T + bias, BMx128 tile, BK=32, fp32 acc.
// R8: back to R5's proven single-buffer 2-barrier k-loop (R6/R7 dbuf was a
// net loss: DMA-write/ds_read LDS contention + occupancy). XCD swizzle kept
// (R6-proven: FETCH 206->60 MB = ideal). NEW: bf16 operands (WBF16/ABF16)
// remove the ~64 v_cvt/wave/k-step that made VALUBusy 3x MfmaUtil, and halve
// staging bytes + LDS.
template <int BM, int ABF16, int WBF16>
__global__ __launch_bounds__(256) void gemm_nt(GemmArgs args) {
  const int N = 1024, K = 1024;

  // XCD-chunked swizzle. Requires gridDim.x == 8 and total blocks % 8 == 0.
  const int NY = gridDim.y;
  const int lin = blockIdx.x + (blockIdx.y << 3) + blockIdx.z * (NY << 3);
  const int chunk = NY * gridDim.z;  // total/8
  const int nid = (lin & 7) * chunk + (lin >> 3);
  const int z = nid / (NY << 3);
  const int rem = nid - z * (NY << 3);
  const int m0 = (rem >> 3) * BM, n0 = (rem & 7) * 128;

  const float* bias = args.bias[z];
  const int out_mode = args.out_mode[z];
  constexpr int MI = BM / 32;

  __shared__ __align__(16) char AsB[ABF16 ? BM * 64 : BM * 128];
  __shared__ __align__(16) char BsB[WBF16 ? 128 * 64 : 128 * 128];

  const int t = threadIdx.x;
  const int wave = t >> 6, lane = t & 63;
  const int lr = lane & 15, quad = lane >> 4;
  const int wm = (wave >> 1) * (BM / 2), wn = (wave & 1) * 64;

  auto stage = [&](int kt) {
    if constexpr (ABF16) {
      const u16* Ab = (const u16*)args.A[z];
      constexpr int NI = BM / 16;  // 1KB wave-instrs for the A tile
#pragma unroll
      for (int j = 0; j < (NI + 3) / 4; j++) {
        const int ii = wave + j * 4;
        if (NI >= 4 || ii < NI) {  // wave-uniform guard
          const int r0 = ii * 16;
          const int row = r0 + (lane >> 2);
          const int cg = (lane & 3) ^ ((lane >> 2) & 3);
          gl2lds16(Ab + (size_t)(m0 + row) * K + kt + cg * 8, AsB + r0 * 64 + lane * 16);
        }
      }
    } else {
      const float* Af = (const float*)args.A[z];
#pragma unroll
      for (int j = 0; j < BM / 32; j++) {
        const int r0 = wave * (BM / 4) + j * 8;
        const int row = r0 + (lane >> 3);
        const int cg = (lane & 7) ^ ((lane >> 3) & 7);
        gl2lds16(Af + (size_t)(m0 + row) * K + kt + cg * 4, AsB + r0 * 128 + lane * 16);
      }
    }
    if constexpr (WBF16) {
      const u16* Wb = (const u16*)args.W[z];
#pragma unroll
      for (int j = 0; j < 2; j++) {
        const int r0 = (wave + j * 4) * 16;
        const int row = r0 + (lane >> 2);
        const int cg = (lane & 3) ^ ((lane >> 2) & 3);
        gl2lds16(Wb + (size_t)(n0 + row) * K + kt + cg * 8, BsB + r0 * 64 + lane * 16);
      }
    } else {
      const float* Wf = (const float*)args.W[z];
#pragma unroll
      for (int j = 0; j < 4; j++) {
        const int r0 = wave * 32 + j * 8;
        const int row = r0 + (lane >> 3);
        const int cg = (lane & 7) ^ ((lane >> 3) & 7);
        gl2lds16(Wf + (size_t)(n0 + row) * K + kt + cg * 4, BsB + r0 * 128 + lane * 16);
      }
    }
  };

  floatx4 acc[MI][4] = {};

  for (int kt = 0; kt < K; kt += 32) {
    __syncthreads();  // prev-iter LDS reads done before overwrite
    stage(kt);
    __syncthreads();  // drains vmcnt(0): tile staged

    bf16x8 af[MI], bf[4];
#pragma unroll
    for (int i = 0; i < MI; i++) {
      const int row = wm + i * 16 + lr;
      if constexpr (ABF16) {
        const int cp = quad ^ (row & 3);
        af[i] = *reinterpret_cast<const bf16x8*>(AsB + row * 64 + cp * 16);
      } else {
        const int e = row & 7;
        const float4 c0 = *reinterpret_cast<const float4*>(AsB + row * 128 + ((2 * quad) ^ e) * 16);
        const float4 c1 = *reinterpret_cast<const float4*>(AsB + row * 128 + ((2 * quad + 1) ^ e) * 16);
        af[i] = cvt8(c0, c1);
      }
    }
#pragma unroll
    for (int i = 0; i < 4; i++) {
      const int row = wn + i * 16 + lr;
      if constexpr (WBF16) {
        const int cp = quad ^ (row & 3);
        bf[i] = *reinterpret_cast<const bf16x8*>(BsB + row * 64 + cp * 16);
      } else {
        const int e = row & 7;
        const float4 c0 = *reinterpret_cast<const float4*>(BsB + row * 128 + ((2 * quad) ^ e) * 16);
        const float4 c1 = *reinterpret_cast<const float4*>(BsB + row * 128 + ((2 * quad + 1) ^ e) * 16);
        bf[i] = cvt8(c0, c1);
      }
    }
#pragma unroll
    for (int mi = 0; mi < MI; mi++)
#pragma unroll
      for (int nf = 0; nf < 4; nf++)
        acc[mi][nf] = MFMA16(af[mi], bf[nf], acc[mi][nf]);
  }

  // epilogue: C-frag col = lane&15, row = quad*4 + reg
#pragma unroll
  for (int nf = 0; nf < 4; nf++) {
    const int col = n0 + wn + nf * 16 + lr;
    const float bv = bias[col];
#pragma unroll
    for (int mi = 0; mi < MI; mi++) {
      const int row0 = m0 + wm + mi * 16 + quad * 4;
      if (out_mode == 0) {
        u16* C = (u16*)args.C[z];
#pragma unroll
        for (int r = 0; r < 4; r++)
          C[(row0 + r) * N + col] = f2bf(acc[mi][nf][r] + bv);
      } else if (out_mode == 1) {
        u16* C = (u16*)args.C[z];
        const int h = col >> 6, d = col & 63;
        const int b = row0 >> 11, s = row0 & 2047;
        ushort4 pk;
        pk.x = f2bf(acc[mi][nf][0] + bv);
        pk.y = f2bf(acc[mi][nf][1] + bv);
        pk.z = f2bf(acc[mi][nf][2] + bv);
        pk.w = f2bf(acc[mi][nf][3] + bv);
        *reinterpret_cast<ushort4*>(&C[((b * 16 + h) * 64 + d) * 2048 + s]) = pk;
      } else {
        float* C = (float*)args.C[z];
#pragma unroll
        for (int r = 0; r < 4; r++)
          C[(row0 + r) * N + col] = acc[mi][nf][r] + bv;
      }
    }
  }
}

// Interleaved RoPE on Q and K in-place (bf16).
// Q gets scale 0.125*log2(e): folds 1/sqrt(D) AND the exp->exp2 domain switch
// used by the in-register softmax in attn_kernel.
__global__ __launch_bounds__(256) void rope_kernel(u16* Q, u16* Kb) {
  const int idx = blockIdx.x * 256 + threadIdx.x;
  const int tensor = idx >> 19;
  const int i = idx & 524287;
  u16* P = tensor ? Kb : Q;
  const int row = i >> 7;
  const int cg = i & 127;
  const int s = row & 2047;
  const int col0 = cg * 8;
  const float scale = tensor ? 1.0f : 0.18033688011112042f;  // 0.125 * log2(e)
  union { uint4 u; u16 h[8]; } v;
  v.u = *reinterpret_cast<const uint4*>(&P[row * 1024 + col0]);
  const int j0 = (col0 & 63) >> 1;
#pragma unroll
  for (int p = 0; p < 4; p++) {
    const int j = j0 + p;
    const float inv = exp2f(-(float)j * (13.287712379549449f / 32.0f));  // 10000^(-j/32)
    const float f = (float)s * inv;
    float sn, cs;
    sincosf(f, &sn, &cs);
    const float e = bf2f(v.h[2 * p]), o = bf2f(v.h[2 * p + 1]);
    v.h[2 * p]     = f2bf((e * cs - o * sn) * scale);
    v.h[2 * p + 1] = f2bf((o * cs + e * sn) * scale);
  }
  *reinterpret_cast<uint4*>(&P[row * 1024 + col0]) = v.u;
}

// P^T fragment build: regs g..g+7 of a 32-reg S^T acc hold
// k = base + (r&3) + 8*(r>>2) + 4*hi (hi = lane>>5), q = lane&31.
// B-operand of mfma32 needs lane to hold k = base + 8*hi + j (j=0..7).
// cvt_pk pairs + v_permlane32_swap_b32 (dst' = [dst.lo, src.lo],
// src' = [dst.hi, src.hi]; partner lane l^32 has the SAME q) produce exactly
// that: wA'=j{0,1}, wC'=j{2,3}, wB'=j{4,5}, wD'=j{6,7}.
#define MAKE_PB(pp, g, out) do {                                              \
    unsigned int wA, wB, wC, wD;                                              \
    asm("v_cvt_pk_bf16_f32 %0, %1, %2" : "=v"(wA) : "v"((pp)[(g)+0]), "v"((pp)[(g)+1])); \
    asm("v_cvt_pk_bf16_f32 %0, %1, %2" : "=v"(wB) : "v"((pp)[(g)+4]), "v"((pp)[(g)+5])); \
    asm("v_cvt_pk_bf16_f32 %0, %1, %2" : "=v"(wC) : "v"((pp)[(g)+2]), "v"((pp)[(g)+3])); \
    asm("v_cvt_pk_bf16_f32 %0, %1, %2" : "=v"(wD) : "v"((pp)[(g)+6]), "v"((pp)[(g)+7])); \
    asm("v_permlane32_swap_b32 %0, %1" : "+v"(wA), "+v"(wB));                 \
    asm("v_permlane32_swap_b32 %0, %1" : "+v"(wC), "+v"(wD));                 \
    union { unsigned int w[4]; bf16x8 v; } u_;                                \
    u_.w[0] = wA; u_.w[1] = wC; u_.w[2] = wB; u_.w[3] = wD;                   \
    (out) = u_.v;                                                             \
  } while (0)

// Flash attention v6 (R5/R6-proven): swapped-operand in-register compute +
// coalesced double-buffered LDS staging + XCD-chunked swizzle. Unchanged.
__global__ __launch_bounds__(256, 2) void attn_kernel(const u16* Q, const u16* K,
                                                      const u16* Vt, u16* O) {
  // grid (16,32) = 512 blocks; chunk = 64/XCD -> 4 consecutive bh per XCD.
  const int lin = blockIdx.x + (blockIdx.y << 4);
  const int nid = (lin & 7) * 64 + (lin >> 3);
  const int bx = nid & 15, bh = nid >> 4;

  const int b = bh >> 4, h = bh & 15;
  const int t = threadIdx.x;
  const int warp = t >> 6, lane = t & 63;
  const int lq = lane & 31, hi = lane >> 5;

  __shared__ __align__(16) u16 Ks[2][64][64];
  __shared__ __align__(16) u16 Vs[2][64][64];

  const int q0 = bx * 128 + warp * 32;

  // Q B-frag: qf[s][j] = Q[q0+lq][h*64 + 16s + 8hi + j]
  const u16* qp = &Q[(size_t)(b * 2048 + q0 + lq) * 1024 + h * 64 + hi * 8];
  bf16x8 qf[4];
#pragma unroll
  for (int s = 0; s < 4; s++) qf[s] = *reinterpret_cast<const bf16x8*>(&qp[s * 16]);

  const u16* kbase = &K[(size_t)b * 2048 * 1024 + h * 64];
  const u16* vbase = &Vt[(size_t)bh * 131072];

  // Staging: lane l writes LDS granule (l&7) of row base+(l>>3); source
  // granule pre-swizzled (l&7)^(l>>3) => LDS granule g of row r holds
  // logical granule g^(r&7). Each warp stages 16 K-rows + 16 V-rows.
  const int srr = lane >> 3;            // 0..7 == dest row & 7
  const int scg = (lane & 7) ^ srr;     // swizzled source granule

  auto stage = [&](int kt2, int bufi) {
#pragma unroll
    for (int j = 0; j < 2; j++) {
      const int r0 = warp * 16 + j * 8;
      const int row = r0 + srr;
      gl2lds16(kbase + (size_t)(kt2 + row) * 1024 + scg * 8, &Ks[bufi][r0][0]);
      gl2lds16(vbase + (size_t)row * 2048 + kt2 + scg * 8, &Vs[bufi][r0][0]);
    }
  };

  floatx16 o0 = {}, o1 = {};
  float m = -1.0e30f, l = 0.0f;

  stage(0, 0);
  int buf = 0;
  for (int kt = 0; kt < 2048; kt += 64) {
    __syncthreads();  // drains vmcnt(0): stage(cur) done; prev-buf reads done
    if (kt + 64 < 2048) stage(kt + 64, buf ^ 1);  // async prefetch overlaps compute

    // K A-frag: kf[kb][s][j] = K[kt+32kb+lq][h*64+16s+8hi+j]
    bf16x8 kf[2][4], vf[4][2];
#pragma unroll
    for (int kb = 0; kb < 2; kb++) {
      const int r = kb * 32 + lq;
#pragma unroll
      for (int s = 0; s < 4; s++)
        kf[kb][s] = *reinterpret_cast<const bf16x8*>(&Ks[buf][r][((s * 2 + hi) ^ (r & 7)) * 8]);
    }
    // Vt A-frag: vf[ks][d][j] = Vt[32d+lq][kt+16ks+8hi+j]
#pragma unroll
    for (int d = 0; d < 2; d++) {
      const int r = d * 32 + lq;
#pragma unroll
      for (int ks = 0; ks < 4; ks++)
        vf[ks][d] = *reinterpret_cast<const bf16x8*>(&Vs[buf][r][((ks * 2 + hi) ^ (r & 7)) * 8]);
    }

    // QK^T: p0/p1 reg r = S^T[k = kt + 32kb + (r&3)+8*(r>>2)+4hi][q0+lq]
    floatx16 p0 = {}, p1 = {};
#pragma unroll
    for (int s = 0; s < 4; s++) {
      p0 = MFMA32(kf[0][s], qf[s], p0);
      p1 = MFMA32(kf[1][s], qf[s], p1);
    }

    // online softmax (log2 domain), q = lq lane-local; partner l^32 has other 32 k
    float mx = p0[0];
#pragma unroll
    for (int r = 1; r < 16; r++) mx = fmaxf(mx, p0[r]);
#pragma unroll
    for (int r = 0; r < 16; r++) mx = fmaxf(mx, p1[r]);
    mx = fmaxf(mx, __shfl_xor(mx, 32, 64));
    if (!__all(mx <= m + 10.0f)) {  // defer-max: P bounded by 2^10
      const float mn = fmaxf(m, mx);
      const float al = __builtin_amdgcn_exp2f(m - mn);
      m = mn;
      l *= al;
#pragma unroll
      for (int r = 0; r < 16; r++) { o0[r] *= al; o1[r] *= al; }
    }
    float sum = 0.0f;
#pragma unroll
    for (int r = 0; r < 16; r++) { p0[r] = __builtin_amdgcn_exp2f(p0[r] - m); sum += p0[r]; }
#pragma unroll
    for (int r = 0; r < 16; r++) { p1[r] = __builtin_amdgcn_exp2f(p1[r] - m); sum += p1[r]; }
    l += sum + __shfl_xor(sum, 32, 64);

    // P^T -> bf16 B-frags (in-register)
    bf16x8 pb0, pb1, pb2, pb3;
    MAKE_PB(p0, 0, pb0);
    MAKE_PB(p0, 8, pb1);
    MAKE_PB(p1, 0, pb2);
    MAKE_PB(p1, 8, pb3);

    // PV: O^T += Vt @ P^T
    o0 = MFMA32(vf[0][0], pb0, o0);
    o1 = MFMA32(vf[0][1], pb0, o1);
    o0 = MFMA32(vf[1][0], pb1, o0);
    o1 = MFMA32(vf[1][1], pb1, o1);
    o0 = MFMA32(vf[2][0], pb2, o0);
    o1 = MFMA32(vf[2][1], pb2, o1);
    o0 = MFMA32(vf[3][0], pb3, o0);
    o1 = MFMA32(vf[3][1], pb3, o1);

    buf ^= 1;
  }

  // epilogue: O^T reg r -> d = (r&3) + 8*(r>>2) + 4hi + 32*dblk, q = q0+lq
  const float rl = 1.0f / l;
  u16* op = &O[(size_t)(b * 2048 + q0 + lq) * 1024 + h * 64 + hi * 4];
#pragma unroll
  for (int rq = 0; rq < 4; rq++) {
    ushort4 s0, s1;
    s0.x = f2bf(o0[4 * rq + 0] * rl); s0.y = f2bf(o0[4 * rq + 1] * rl);
    s0.z = f2bf(o0[4 * rq + 2] * rl); s0.w = f2bf(o0[4 * rq + 3] * rl);
    s1.x = f2bf(o1[4 * rq + 0] * rl); s1.y = f2bf(o1[4 * rq + 1] * rl);
    s1.z = f2bf(o1[4 * rq + 2] * rl); s1.w = f2bf(o1[4 * rq + 3] * rl);
    *reinterpret_cast<ushort4*>(&op[rq * 8]) = s0;
    *reinterpret_cast<ushort4*>(&op[rq * 8 + 32]) = s1;
  }
}

extern "C" void kernel_launch(void* const* d_in, const int* in_sizes, int n_in,
                              void* d_out, int out_size, void* d_ws, size_t ws_size,
                              hipStream_t stream) {
  (void)in_sizes; (void)n_in; (void)out_size;
  const float* query = (const float*)d_in[0];
  const float* key   = (const float*)d_in[1];
  const float* value = (const float*)d_in[2];
  const float* Wq = (const float*)d_in[3];
  const float* bq = (const float*)d_in[4];
  const float* Wk = (const float*)d_in[5];
  const float* bk = (const float*)d_in[6];
  const float* Wv = (const float*)d_in[7];
  const float* bv = (const float*)d_in[8];
  const float* Wo = (const float*)d_in[9];
  const float* bo = (const float*)d_in[10];

  // Workspace layout (bytes):
  //   Qb  [0,        8.4 MB)   attn Q / attn out (bf16)
  //   Wbf [8.4 MB,  14.7 MB)   Wq,Wk,Wv,... actually Wq,Wk,Wv + Wo bf16? see below
  //   Abf [14.7 MB, 39.8 MB)   query,key,value bf16
  // Kb + Vt (16 MB bf16) live inside d_out (dead until final fp32 GEMM).
  u16* Qb = (u16*)d_ws;
  u16* Kb = (u16*)d_out;
  u16* Vt = (u16*)d_out + 4194304;

  // Wbf holds 4 matrices? No: Wq/Wk/Wv for QKV; Wo reuses Wq's slot AFTER the
  // QKV GEMM is done? Wq slot still needed? No — QKV GEMM completes before
  // proj launches, but stream ordering means we must convert Wo before proj;
  // simplest: Wbf sized for 3 (QKV) and convert Wo into Wbf slot 0 is unsafe
  // under graph capture? It's the same stream, strictly ordered: safe. But
  // keep it simple and robust: convert all 4 up front into 4 slots.
  const bool haveW = ws_size >= (size_t)(8388608 + 4 * 2097152);            // Qb + 4 W's
  const bool haveA = ws_size >= (size_t)(8388608 + 4 * 2097152 + 25165824); // + 3 A's
  u16* Wbf = (u16*)d_ws + 4194304;             // 4 x 1M u16
  u16* Abf = (u16*)d_ws + 4194304 + 4194304;   // 3 x 4M u16

  if (haveW) {
    CvtArgs cw;
    cw.src[0] = Wq; cw.dst[0] = Wbf;
    cw.src[1] = Wk; cw.dst[1] = Wbf + 1048576;
    cw.src[2] = Wv; cw.dst[2] = Wbf + 2097152;
    cvt_kernel<<<dim3(512, 1, 3), dim3(256), 0, stream>>>(cw);
    CvtArgs co;  // Wo alone (count differs from A class)
    co.src[0] = Wo; co.dst[0] = Wbf + 3145728;
    co.src[1] = Wo; co.dst[1] = Wbf + 3145728;  // unused z guard: grid.z=1
    co.src[2] = Wo; co.dst[2] = Wbf + 3145728;
    cvt_kernel<<<dim3(512, 1, 1), dim3(256), 0, stream>>>(co);
  }
  if (haveA) {
    CvtArgs ca;
    ca.src[0] = query; ca.dst[0] = Abf;
    ca.src[1] = key;   ca.dst[1] = Abf + 4194304;
    ca.src[2] = value; ca.dst[2] = Abf + 8388608;
    cvt_kernel<<<dim3(2048, 1, 3), dim3(256), 0, stream>>>(ca);
  }

  GemmArgs g1;
  g1.bias[0] = bq; g1.C[0] = Qb; g1.out_mode[0] = 0;
  g1.bias[1] = bk; g1.C[1] = Kb; g1.out_mode[1] = 0;
  g1.bias[2] = bv; g1.C[2] = Vt; g1.out_mode[2] = 1;
  if (haveA) {
    g1.A[0] = Abf; g1.A[1] = Abf + 4194304; g1.A[2] = Abf + 8388608;
  } else {
    g1.A[0] = query; g1.A[1] = key; g1.A[2] = value;
  }
  if (haveW) {
    g1.W[0] = Wbf; g1.W[1] = Wbf + 1048576; g1.W[2] = Wbf + 2097152;
  } else {
    g1.W[0] = Wq; g1.W[1] = Wk; g1.W[2] = Wv;
  }
  // BM=128 -> grid (8,32,3) = 768 blocks, single-buffer 2-barrier (R5-proven).
  if (haveA && haveW)
    gemm_nt<128, 1, 1><<<dim3(8, 32, 3), dim3(256), 0, stream>>>(g1);
  else if (haveW)
    gemm_nt<128, 0, 1><<<dim3(8, 32, 3), dim3(256), 0, stream>>>(g1);
  else
    gemm_nt<128, 0, 0><<<dim3(8, 32, 3), dim3(256), 0, stream>>>(g1);

  rope_kernel<<<dim3(4096), dim3(256), 0, stream>>>(Qb, Kb);

  attn_kernel<<<dim3(16, 32), dim3(256), 0, stream>>>(Qb, Kb, Vt, Qb);

  // Final projection: bf16 attn output -> fp32 d_out. BM=64 -> 512 blocks.
  GemmArgs g2;
  for (int i = 0; i < 3; i++) {
    g2.A[i] = Qb; g2.bias[i] = bo;
    g2.C[i] = d_out; g2.out_mode[i] = 2;
    g2.W[i] = haveW ? (const void*)(Wbf + 3145728) : (const void*)Wo;
  }
  if (haveW)
    gemm_nt<64, 1, 1><<<dim3(8, 64, 1), dim3(256), 0, stream>>>(g2);
  else
    gemm_nt<64, 1, 0><<<dim3(8, 64, 1), dim3(256), 0, stream>>>(g2);
}

// Round 9
// 227.930 us; speedup vs baseline: 1.2461x; 1.0139x over previous
//
#include <hip/hip_runtime.h>
#include <math.h>

typedef unsigned short u16;
typedef __bf16 bf16x8 __attribute__((ext_vector_type(8)));
typedef float floatx4 __attribute__((ext_vector_type(4)));
typedef float floatx16 __attribute__((ext_vector_type(16)));

#define MFMA16(a, b, c) __builtin_amdgcn_mfma_f32_16x16x32_bf16((a), (b), (c), 0, 0, 0)
#define MFMA32(a, b, c) __builtin_amdgcn_mfma_f32_32x32x16_bf16((a), (b), (c), 0, 0, 0)

__device__ __forceinline__ float bf2f(u16 u) {
  union { float f; unsigned int i; } v; v.i = ((unsigned int)u) << 16; return v.f;
}
__device__ __forceinline__ u16 f2bf(float f) {  // native RNE cvt
  __bf16 h = (__bf16)f;
  union { __bf16 h; u16 u; } v; v.h = h; return v.u;
}
__device__ __forceinline__ bf16x8 cvt8(float4 a, float4 b) {
  bf16x8 r;
  r[0] = (__bf16)a.x; r[1] = (__bf16)a.y; r[2] = (__bf16)a.z; r[3] = (__bf16)a.w;
  r[4] = (__bf16)b.x; r[5] = (__bf16)b.y; r[6] = (__bf16)b.z; r[7] = (__bf16)b.w;
  return r;
}
// Async global->LDS, 16 B per lane. LDS dest = wave-uniform base + lane*16.
__device__ __forceinline__ void gl2lds16(const void* g, void* l) {
  __builtin_amdgcn_global_load_lds(
      (const __attribute__((address_space(1))) unsigned int*)g,
      (__attribute__((address_space(3))) unsigned int*)l, 16, 0, 0);
}

// fp32 -> bf16 elementwise, 8 elems/thread (32B read, 16B write, coalesced).
struct CvtArgs { const float* src[4]; u16* dst[4]; };
__global__ __launch_bounds__(256) void cvt_kernel(CvtArgs a) {
  const float* s = a.src[blockIdx.z];
  u16* d = a.dst[blockIdx.z];
  const int i = (blockIdx.x * 256 + threadIdx.x) * 8;
  const float4 x = *reinterpret_cast<const float4*>(s + i);
  const float4 y = *reinterpret_cast<const float4*>(s + i + 4);
  *reinterpret_cast<bf16x8*>(&d[i]) = cvt8(x, y);
}

struct GemmArgs {
  const void* A[3];     // fp32 (ABF16=0) or bf16 (ABF16=1) [.,1024]
  const void* W[3];     // fp32 (WBF16=0) or bf16 (WBF16=1) [1024,1024], B^T (NT)
  const float* bias[3]; // fp32 [1024]
  void* C[3];
  int out_mode[3];      // 0 = bf16, 1 = bf16 Vt[b,h,d,s], 2 = fp32
};

// C[.,1024] = A @ W^T + bias, BMx128 tile, BK=32, fp32 acc.
// R8-proven: single-buffer 2-barrier k-loop, bf16 operands, XCD swizzle.
template <int BM, int ABF16, int WBF16>
__global__ __launch_bounds__(256) void gemm_nt(GemmArgs args) {
  const int N = 1024, K = 1024;

  // XCD-chunked swizzle. Requires gridDim.x == 8 and total blocks % 8 == 0.
  const int NY = gridDim.y;
  const int lin = blockIdx.x + (blockIdx.y << 3) + blockIdx.z * (NY << 3);
  const int chunk = NY * gridDim.z;  // total/8
  const int nid = (lin & 7) * chunk + (lin >> 3);
  const int z = nid / (NY << 3);
  const int rem = nid - z * (NY << 3);
  const int m0 = (rem >> 3) * BM, n0 = (rem & 7) * 128;

  const float* bias = args.bias[z];
  const int out_mode = args.out_mode[z];
  constexpr int MI = BM / 32;

  __shared__ __align__(16) char AsB[ABF16 ? BM * 64 : BM * 128];
  __shared__ __align__(16) char BsB[WBF16 ? 128 * 64 : 128 * 128];

  const int t = threadIdx.x;
  const int wave = t >> 6, lane = t & 63;
  const int lr = lane & 15, quad = lane >> 4;
  const int wm = (wave >> 1) * (BM / 2), wn = (wave & 1) * 64;

  auto stage = [&](int kt) {
    if constexpr (ABF16) {
      const u16* Ab = (const u16*)args.A[z];
      constexpr int NI = BM / 16;  // 1KB wave-instrs for the A tile
#pragma unroll
      for (int j = 0; j < (NI + 3) / 4; j++) {
        const int ii = wave + j * 4;
        if (NI >= 4 || ii < NI) {  // wave-uniform guard
          const int r0 = ii * 16;
          const int row = r0 + (lane >> 2);
          const int cg = (lane & 3) ^ ((lane >> 2) & 3);
          gl2lds16(Ab + (size_t)(m0 + row) * K + kt + cg * 8, AsB + r0 * 64 + lane * 16);
        }
      }
    } else {
      const float* Af = (const float*)args.A[z];
#pragma unroll
      for (int j = 0; j < BM / 32; j++) {
        const int r0 = wave * (BM / 4) + j * 8;
        const int row = r0 + (lane >> 3);
        const int cg = (lane & 7) ^ ((lane >> 3) & 7);
        gl2lds16(Af + (size_t)(m0 + row) * K + kt + cg * 4, AsB + r0 * 128 + lane * 16);
      }
    }
    if constexpr (WBF16) {
      const u16* Wb = (const u16*)args.W[z];
#pragma unroll
      for (int j = 0; j < 2; j++) {
        const int r0 = (wave + j * 4) * 16;
        const int row = r0 + (lane >> 2);
        const int cg = (lane & 3) ^ ((lane >> 2) & 3);
        gl2lds16(Wb + (size_t)(n0 + row) * K + kt + cg * 8, BsB + r0 * 64 + lane * 16);
      }
    } else {
      const float* Wf = (const float*)args.W[z];
#pragma unroll
      for (int j = 0; j < 4; j++) {
        const int r0 = wave * 32 + j * 8;
        const int row = r0 + (lane >> 3);
        const int cg = (lane & 7) ^ ((lane >> 3) & 7);
        gl2lds16(Wf + (size_t)(n0 + row) * K + kt + cg * 4, BsB + r0 * 128 + lane * 16);
      }
    }
  };

  floatx4 acc[MI][4] = {};

  for (int kt = 0; kt < K; kt += 32) {
    __syncthreads();  // prev-iter LDS reads done before overwrite
    stage(kt);
    __syncthreads();  // drains vmcnt(0): tile staged

    bf16x8 af[MI], bf[4];
#pragma unroll
    for (int i = 0; i < MI; i++) {
      const int row = wm + i * 16 + lr;
      if constexpr (ABF16) {
        const int cp = quad ^ (row & 3);
        af[i] = *reinterpret_cast<const bf16x8*>(AsB + row * 64 + cp * 16);
      } else {
        const int e = row & 7;
        const float4 c0 = *reinterpret_cast<const float4*>(AsB + row * 128 + ((2 * quad) ^ e) * 16);
        const float4 c1 = *reinterpret_cast<const float4*>(AsB + row * 128 + ((2 * quad + 1) ^ e) * 16);
        af[i] = cvt8(c0, c1);
      }
    }
#pragma unroll
    for (int i = 0; i < 4; i++) {
      const int row = wn + i * 16 + lr;
      if constexpr (WBF16) {
        const int cp = quad ^ (row & 3);
        bf[i] = *reinterpret_cast<const bf16x8*>(BsB + row * 64 + cp * 16);
      } else {
        const int e = row & 7;
        const float4 c0 = *reinterpret_cast<const float4*>(BsB + row * 128 + ((2 * quad) ^ e) * 16);
        const float4 c1 = *reinterpret_cast<const float4*>(BsB + row * 128 + ((2 * quad + 1) ^ e) * 16);
        bf[i] = cvt8(c0, c1);
      }
    }
#pragma unroll
    for (int mi = 0; mi < MI; mi++)
#pragma unroll
      for (int nf = 0; nf < 4; nf++)
        acc[mi][nf] = MFMA16(af[mi], bf[nf], acc[mi][nf]);
  }

  // epilogue: C-frag col = lane&15, row = quad*4 + reg
#pragma unroll
  for (int nf = 0; nf < 4; nf++) {
    const int col = n0 + wn + nf * 16 + lr;
    const float bv = bias[col];
#pragma unroll
    for (int mi = 0; mi < MI; mi++) {
      const int row0 = m0 + wm + mi * 16 + quad * 4;
      if (out_mode == 0) {
        u16* C = (u16*)args.C[z];
#pragma unroll
        for (int r = 0; r < 4; r++)
          C[(row0 + r) * N + col] = f2bf(acc[mi][nf][r] + bv);
      } else if (out_mode == 1) {
        u16* C = (u16*)args.C[z];
        const int h = col >> 6, d = col & 63;
        const int b = row0 >> 11, s = row0 & 2047;
        ushort4 pk;
        pk.x = f2bf(acc[mi][nf][0] + bv);
        pk.y = f2bf(acc[mi][nf][1] + bv);
        pk.z = f2bf(acc[mi][nf][2] + bv);
        pk.w = f2bf(acc[mi][nf][3] + bv);
        *reinterpret_cast<ushort4*>(&C[((b * 16 + h) * 64 + d) * 2048 + s]) = pk;
      } else {
        float* C = (float*)args.C[z];
#pragma unroll
        for (int r = 0; r < 4; r++)
          C[(row0 + r) * N + col] = acc[mi][nf][r] + bv;
      }
    }
  }
}

// Interleaved RoPE on K in-place (bf16). Q-rope is fused into attn_kernel
// (in-register, with the 0.125*log2e scale fold).
__global__ __launch_bounds__(256) void rope_kernel(u16* Kb) {
  const int idx = blockIdx.x * 256 + threadIdx.x;  // 524288 threads
  const int row = idx >> 7;
  const int cg = idx & 127;
  const int s = row & 2047;
  const int col0 = cg * 8;
  union { uint4 u; u16 h[8]; } v;
  v.u = *reinterpret_cast<const uint4*>(&Kb[row * 1024 + col0]);
  const int j0 = (col0 & 63) >> 1;
#pragma unroll
  for (int p = 0; p < 4; p++) {
    const int j = j0 + p;
    const float inv = exp2f(-(float)j * (13.287712379549449f / 32.0f));  // 10000^(-j/32)
    const float f = (float)s * inv;
    float sn, cs;
    sincosf(f, &sn, &cs);
    const float e = bf2f(v.h[2 * p]), o = bf2f(v.h[2 * p + 1]);
    v.h[2 * p]     = f2bf(e * cs - o * sn);
    v.h[2 * p + 1] = f2bf(o * cs + e * sn);
  }
  *reinterpret_cast<uint4*>(&Kb[row * 1024 + col0]) = v.u;
}

// P^T fragment build: regs g..g+7 of a 32-reg S^T acc hold
// k = base + (r&3) + 8*(r>>2) + 4*hi (hi = lane>>5), q = lane&31.
// B-operand of mfma32 needs lane to hold k = base + 8*hi + j (j=0..7).
// cvt_pk pairs + v_permlane32_swap_b32 (dst' = [dst.lo, src.lo],
// src' = [dst.hi, src.hi]; partner lane l^32 has the SAME q) produce exactly
// that: wA'=j{0,1}, wC'=j{2,3}, wB'=j{4,5}, wD'=j{6,7}.
#define MAKE_PB(pp, g, out) do {                                              \
    unsigned int wA, wB, wC, wD;                                              \
    asm("v_cvt_pk_bf16_f32 %0, %1, %2" : "=v"(wA) : "v"((pp)[(g)+0]), "v"((pp)[(g)+1])); \
    asm("v_cvt_pk_bf16_f32 %0, %1, %2" : "=v"(wB) : "v"((pp)[(g)+4]), "v"((pp)[(g)+5])); \
    asm("v_cvt_pk_bf16_f32 %0, %1, %2" : "=v"(wC) : "v"((pp)[(g)+2]), "v"((pp)[(g)+3])); \
    asm("v_cvt_pk_bf16_f32 %0, %1, %2" : "=v"(wD) : "v"((pp)[(g)+6]), "v"((pp)[(g)+7])); \
    asm("v_permlane32_swap_b32 %0, %1" : "+v"(wA), "+v"(wB));                 \
    asm("v_permlane32_swap_b32 %0, %1" : "+v"(wC), "+v"(wD));                 \
    union { unsigned int w[4]; bf16x8 v; } u_;                                \
    u_.w[0] = wA; u_.w[1] = wC; u_.w[2] = wB; u_.w[3] = wD;                   \
    (out) = u_.v;                                                             \
  } while (0)

// Flash attention v7 (R8 post-mortem): R5/R8-proven structure +
//  - 4 LDS slots, 2 tiles staged per barrier -> 16 barriers instead of 32
//    (R8 diagnosis: 2 waves/SIMD hard cap -> barrier/dep stalls dominate;
//    65% combined pipe busy). stage()/frag-read code unchanged, slots only.
//  - s_setprio(1) around MFMA clusters (T5, attn-proven).
//  - Q-RoPE fused in-register at Q-load (16 sincos once per warp; pairs are
//    lane-local in the frag layout). rope_kernel is now K-only.
__global__ __launch_bounds__(256, 2) void attn_kernel(const u16* Q, const u16* K,
                                                      const u16* Vt, u16* O) {
  // grid (16,32) = 512 blocks; chunk = 64/XCD -> 4 consecutive bh per XCD.
  const int lin = blockIdx.x + (blockIdx.y << 4);
  const int nid = (lin & 7) * 64 + (lin >> 3);
  const int bx = nid & 15, bh = nid >> 4;

  const int b = bh >> 4, h = bh & 15;
  const int t = threadIdx.x;
  const int warp = t >> 6, lane = t & 63;
  const int lq = lane & 31, hi = lane >> 5;

  __shared__ __align__(16) u16 Ks[4][64][64];
  __shared__ __align__(16) u16 Vs[4][64][64];

  const int q0 = bx * 128 + warp * 32;

  // Q B-frag: qf[s][j] = Q[q0+lq][h*64 + 16s + 8hi + j]
  const u16* qp = &Q[(size_t)(b * 2048 + q0 + lq) * 1024 + h * 64 + hi * 8];
  bf16x8 qf[4];
#pragma unroll
  for (int s = 0; s < 4; s++) qf[s] = *reinterpret_cast<const bf16x8*>(&qp[s * 16]);

  // In-register RoPE on Q + scale fold (0.125 * log2e). d = 16s+8hi+j;
  // pair p covers d = {16s+8hi+2p, +1} -> pair index jp = 8s+4hi+p.
  {
    const float seqf = (float)(q0 + lq);
#pragma unroll
    for (int s = 0; s < 4; s++) {
#pragma unroll
      for (int p = 0; p < 4; p++) {
        const int jp = s * 8 + hi * 4 + p;
        const float inv = exp2f(-(float)jp * (13.287712379549449f / 32.0f));
        float sn, cs;
        sincosf(seqf * inv, &sn, &cs);
        const float e = (float)qf[s][2 * p], o = (float)qf[s][2 * p + 1];
        qf[s][2 * p]     = (__bf16)((e * cs - o * sn) * 0.18033688011112042f);
        qf[s][2 * p + 1] = (__bf16)((o * cs + e * sn) * 0.18033688011112042f);
      }
    }
  }

  const u16* kbase = &K[(size_t)b * 2048 * 1024 + h * 64];
  const u16* vbase = &Vt[(size_t)bh * 131072];

  // Staging: lane l writes LDS granule (l&7) of row base+(l>>3); source
  // granule pre-swizzled (l&7)^(l>>3) => LDS granule g of row r holds
  // logical granule g^(r&7). Each warp stages 16 K-rows + 16 V-rows.
  const int srr = lane >> 3;            // 0..7 == dest row & 7
  const int scg = (lane & 7) ^ srr;     // swizzled source granule

  auto stage = [&](int kt2, int slot) {
#pragma unroll
    for (int j = 0; j < 2; j++) {
      const int r0 = warp * 16 + j * 8;
      const int row = r0 + srr;
      gl2lds16(kbase + (size_t)(kt2 + row) * 1024 + scg * 8, &Ks[slot][r0][0]);
      gl2lds16(vbase + (size_t)row * 2048 + kt2 + scg * 8, &Vs[slot][r0][0]);
    }
  };

  floatx16 o0 = {}, o1 = {};
  float m = -1.0e30f, l = 0.0f;

  auto compute = [&](int buf) {
    // K A-frag: kf[kb][s][j] = K[kt+32kb+lq][h*64+16s+8hi+j]
    bf16x8 kf[2][4], vf[4][2];
#pragma unroll
    for (int kb = 0; kb < 2; kb++) {
      const int r = kb * 32 + lq;
#pragma unroll
      for (int s = 0; s < 4; s++)
        kf[kb][s] = *reinterpret_cast<const bf16x8*>(&Ks[buf][r][((s * 2 + hi) ^ (r & 7)) * 8]);
    }
    // Vt A-frag: vf[ks][d][j] = Vt[32d+lq][kt+16ks+8hi+j]
#pragma unroll
    for (int d = 0; d < 2; d++) {
      const int r = d * 32 + lq;
#pragma unroll
      for (int ks = 0; ks < 4; ks++)
        vf[ks][d] = *reinterpret_cast<const bf16x8*>(&Vs[buf][r][((ks * 2 + hi) ^ (r & 7)) * 8]);
    }

    // QK^T: p0/p1 reg r = S^T[k = kt + 32kb + (r&3)+8*(r>>2)+4hi][q0+lq]
    floatx16 p0 = {}, p1 = {};
    __builtin_amdgcn_s_setprio(1);
#pragma unroll
    for (int s = 0; s < 4; s++) {
      p0 = MFMA32(kf[0][s], qf[s], p0);
      p1 = MFMA32(kf[1][s], qf[s], p1);
    }
    __builtin_amdgcn_s_setprio(0);

    // online softmax (log2 domain), q = lq lane-local; partner l^32 has other 32 k
    float mx = p0[0];
#pragma unroll
    for (int r = 1; r < 16; r++) mx = fmaxf(mx, p0[r]);
#pragma unroll
    for (int r = 0; r < 16; r++) mx = fmaxf(mx, p1[r]);
    mx = fmaxf(mx, __shfl_xor(mx, 32, 64));
    if (!__all(mx <= m + 10.0f)) {  // defer-max: P bounded by 2^10
      const float mn = fmaxf(m, mx);
      const float al = __builtin_amdgcn_exp2f(m - mn);
      m = mn;
      l *= al;
#pragma unroll
      for (int r = 0; r < 16; r++) { o0[r] *= al; o1[r] *= al; }
    }
    float sum = 0.0f;
#pragma unroll
    for (int r = 0; r < 16; r++) { p0[r] = __builtin_amdgcn_exp2f(p0[r] - m); sum += p0[r]; }
#pragma unroll
    for (int r = 0; r < 16; r++) { p1[r] = __builtin_amdgcn_exp2f(p1[r] - m); sum += p1[r]; }
    l += sum + __shfl_xor(sum, 32, 64);

    // P^T -> bf16 B-frags (in-register)
    bf16x8 pb0, pb1, pb2, pb3;
    MAKE_PB(p0, 0, pb0);
    MAKE_PB(p0, 8, pb1);
    MAKE_PB(p1, 0, pb2);
    MAKE_PB(p1, 8, pb3);

    // PV: O^T += Vt @ P^T
    __builtin_amdgcn_s_setprio(1);
    o0 = MFMA32(vf[0][0], pb0, o0);
    o1 = MFMA32(vf[0][1], pb0, o1);
    o0 = MFMA32(vf[1][0], pb1, o0);
    o1 = MFMA32(vf[1][1], pb1, o1);
    o0 = MFMA32(vf[2][0], pb2, o0);
    o1 = MFMA32(vf[2][1], pb2, o1);
    o0 = MFMA32(vf[3][0], pb3, o0);
    o1 = MFMA32(vf[3][1], pb3, o1);
    __builtin_amdgcn_s_setprio(0);
  };

  stage(0, 0);
  stage(64, 1);
  for (int kt = 0; kt < 2048; kt += 128) {
    const int s0 = (kt >> 6) & 3;  // 0,2,0,2,...
    __syncthreads();  // drains vmcnt(0): slots s0,s0+1 staged; s0^2 reads done
    if (kt + 128 < 2048) {
      stage(kt + 128, s0 ^ 2);
      stage(kt + 192, (s0 ^ 2) | 1);
    }
    compute(s0);
    compute(s0 | 1);
  }

  // epilogue: O^T reg r -> d = (r&3) + 8*(r>>2) + 4hi + 32*dblk, q = q0+lq
  const float rl = 1.0f / l;
  u16* op = &O[(size_t)(b * 2048 + q0 + lq) * 1024 + h * 64 + hi * 4];
#pragma unroll
  for (int rq = 0; rq < 4; rq++) {
    ushort4 s0, s1;
    s0.x = f2bf(o0[4 * rq + 0] * rl); s0.y = f2bf(o0[4 * rq + 1] * rl);
    s0.z = f2bf(o0[4 * rq + 2] * rl); s0.w = f2bf(o0[4 * rq + 3] * rl);
    s1.x = f2bf(o1[4 * rq + 0] * rl); s1.y = f2bf(o1[4 * rq + 1] * rl);
    s1.z = f2bf(o1[4 * rq + 2] * rl); s1.w = f2bf(o1[4 * rq + 3] * rl);
    *reinterpret_cast<ushort4*>(&op[rq * 8]) = s0;
    *reinterpret_cast<ushort4*>(&op[rq * 8 + 32]) = s1;
  }
}

extern "C" void kernel_launch(void* const* d_in, const int* in_sizes, int n_in,
                              void* d_out, int out_size, void* d_ws, size_t ws_size,
                              hipStream_t stream) {
  (void)in_sizes; (void)n_in; (void)out_size;
  const float* query = (const float*)d_in[0];
  const float* key   = (const float*)d_in[1];
  const float* value = (const float*)d_in[2];
  const float* Wq = (const float*)d_in[3];
  const float* bq = (const float*)d_in[4];
  const float* Wk = (const float*)d_in[5];
  const float* bk = (const float*)d_in[6];
  const float* Wv = (const float*)d_in[7];
  const float* bv = (const float*)d_in[8];
  const float* Wo = (const float*)d_in[9];
  const float* bo = (const float*)d_in[10];

  // Workspace: Qb [0, 8.4 MB) | Wbf 4x2 MB | Abf 3x8.4 MB.
  // Kb + Vt (16 MB bf16) live inside d_out (dead until final fp32 GEMM).
  u16* Qb = (u16*)d_ws;
  u16* Kb = (u16*)d_out;
  u16* Vt = (u16*)d_out + 4194304;

  const bool haveW = ws_size >= (size_t)(8388608 + 4 * 2097152);            // Qb + 4 W's
  const bool haveA = ws_size >= (size_t)(8388608 + 4 * 2097152 + 25165824); // + 3 A's
  u16* Wbf = (u16*)d_ws + 4194304;             // 4 x 1M u16
  u16* Abf = (u16*)d_ws + 4194304 + 4194304;   // 3 x 4M u16

  if (haveW) {
    CvtArgs cw;
    cw.src[0] = Wq; cw.dst[0] = Wbf;
    cw.src[1] = Wk; cw.dst[1] = Wbf + 1048576;
    cw.src[2] = Wv; cw.dst[2] = Wbf + 2097152;
    cw.src[3] = Wo; cw.dst[3] = Wbf + 3145728;
    cvt_kernel<<<dim3(512, 1, 4), dim3(256), 0, stream>>>(cw);
  }
  if (haveA) {
    CvtArgs ca;
    ca.src[0] = query; ca.dst[0] = Abf;
    ca.src[1] = key;   ca.dst[1] = Abf + 4194304;
    ca.src[2] = value; ca.dst[2] = Abf + 8388608;
    ca.src[3] = query; ca.dst[3] = Abf;  // unused (grid.z = 3)
    cvt_kernel<<<dim3(2048, 1, 3), dim3(256), 0, stream>>>(ca);
  }

  GemmArgs g1;
  g1.bias[0] = bq; g1.C[0] = Qb; g1.out_mode[0] = 0;
  g1.bias[1] = bk; g1.C[1] = Kb; g1.out_mode[1] = 0;
  g1.bias[2] = bv; g1.C[2] = Vt; g1.out_mode[2] = 1;
  if (haveA) {
    g1.A[0] = Abf; g1.A[1] = Abf + 4194304; g1.A[2] = Abf + 8388608;
  } else {
    g1.A[0] = query; g1.A[1] = key; g1.A[2] = value;
  }
  if (haveW) {
    g1.W[0] = Wbf; g1.W[1] = Wbf + 1048576; g1.W[2] = Wbf + 2097152;
  } else {
    g1.W[0] = Wq; g1.W[1] = Wk; g1.W[2] = Wv;
  }
  // BM=128 -> grid (8,32,3) = 768 blocks, single-buffer 2-barrier (R5-proven).
  if (haveA && haveW)
    gemm_nt<128, 1, 1><<<dim3(8, 32, 3), dim3(256), 0, stream>>>(g1);
  else if (haveW)
    gemm_nt<128, 0, 1><<<dim3(8, 32, 3), dim3(256), 0, stream>>>(g1);
  else
    gemm_nt<128, 0, 0><<<dim3(8, 32, 3), dim3(256), 0, stream>>>(g1);

  // K-only RoPE (Q-rope fused into attn).
  rope_kernel<<<dim3(2048), dim3(256), 0, stream>>>(Kb);

  attn_kernel<<<dim3(16, 32), dim3(256), 0, stream>>>(Qb, Kb, Vt, Qb);

  // Final projection: bf16 attn output -> fp32 d_out. BM=64 -> 512 blocks.
  GemmArgs g2;
  for (int i = 0; i < 3; i++) {
    g2.A[i] = Qb; g2.bias[i] = bo;
    g2.C[i] = d_out; g2.out_mode[i] = 2;
    g2.W[i] = haveW ? (const void*)(Wbf + 3145728) : (const void*)Wo;
  }
  if (haveW)
    gemm_nt<64, 1, 1><<<dim3(8, 64, 1), dim3(256), 0, stream>>>(g2);
  else
    gemm_nt<64, 1, 0><<<dim3(8, 64, 1), dim3(256), 0, stream>>>(g2);
}

// Round 10
// 224.419 us; speedup vs baseline: 1.2656x; 1.0156x over previous
//
#include <hip/hip_runtime.h>
#include <math.h>

typedef unsigned short u16;
typedef __bf16 bf16x8 __attribute__((ext_vector_type(8)));
typedef float floatx4 __attribute__((ext_vector_type(4)));
typedef float floatx16 __attribute__((ext_vector_type(16)));

#define MFMA16(a, b, c) __builtin_amdgcn_mfma_f32_16x16x32_bf16((a), (b), (c), 0, 0, 0)
#define MFMA32(a, b, c) __builtin_amdgcn_mfma_f32_32x32x16_bf16((a), (b), (c), 0, 0, 0)

__device__ __forceinline__ float bf2f(u16 u) {
  union { float f; unsigned int i; } v; v.i = ((unsigned int)u) << 16; return v.f;
}
__device__ __forceinline__ u16 f2bf(float f) {  // native RNE cvt
  __bf16 h = (__bf16)f;
  union { __bf16 h; u16 u; } v; v.h = h; return v.u;
}
__device__ __forceinline__ bf16x8 cvt8(float4 a, float4 b) {
  bf16x8 r;
  r[0] = (__bf16)a.x; r[1] = (__bf16)a.y; r[2] = (__bf16)a.z; r[3] = (__bf16)a.w;
  r[4] = (__bf16)b.x; r[5] = (__bf16)b.y; r[6] = (__bf16)b.z; r[7] = (__bf16)b.w;
  return r;
}
// Async global->LDS, 16 B per lane. LDS dest = wave-uniform base + lane*16.
__device__ __forceinline__ void gl2lds16(const void* g, void* l) {
  __builtin_amdgcn_global_load_lds(
      (const __attribute__((address_space(1))) unsigned int*)g,
      (__attribute__((address_space(3))) unsigned int*)l, 16, 0, 0);
}

// fp32 -> bf16 elementwise, 8 elems/thread (32B read, 16B write, coalesced).
struct CvtArgs { const float* src[4]; u16* dst[4]; };
__global__ __launch_bounds__(256) void cvt_kernel(CvtArgs a) {
  const float* s = a.src[blockIdx.z];
  u16* d = a.dst[blockIdx.z];
  const int i = (blockIdx.x * 256 + threadIdx.x) * 8;
  const float4 x = *reinterpret_cast<const float4*>(s + i);
  const float4 y = *reinterpret_cast<const float4*>(s + i + 4);
  *reinterpret_cast<bf16x8*>(&d[i]) = cvt8(x, y);
}

struct GemmArgs {
  const void* A[3];     // fp32 (ABF16=0) or bf16 (ABF16=1) [.,1024]
  const void* W[3];     // fp32 (WBF16=0) or bf16 (WBF16=1) [1024,1024], B^T (NT)
  const float* bias[3]; // fp32 [1024]
  void* C[3];
  int out_mode[3];      // 0 = bf16, 1 = bf16 Vt[b,h,d,s], 2 = fp32
};

// C[.,1024] = A @ W^T + bias, BMx128 tile, BK=32, fp32 acc.
// R8-proven: single-buffer 2-barrier k-loop, bf16 operands, XCD swizzle.
template <int BM, int ABF16, int WBF16>
__global__ __launch_bounds__(256) void gemm_nt(GemmArgs args) {
  const int N = 1024, K = 1024;

  // XCD-chunked swizzle. Requires gridDim.x == 8 and total blocks % 8 == 0.
  const int NY = gridDim.y;
  const int lin = blockIdx.x + (blockIdx.y << 3) + blockIdx.z * (NY << 3);
  const int chunk = NY * gridDim.z;  // total/8
  const int nid = (lin & 7) * chunk + (lin >> 3);
  const int z = nid / (NY << 3);
  const int rem = nid - z * (NY << 3);
  const int m0 = (rem >> 3) * BM, n0 = (rem & 7) * 128;

  const float* bias = args.bias[z];
  const int out_mode = args.out_mode[z];
  constexpr int MI = BM / 32;

  __shared__ __align__(16) char AsB[ABF16 ? BM * 64 : BM * 128];
  __shared__ __align__(16) char BsB[WBF16 ? 128 * 64 : 128 * 128];

  const int t = threadIdx.x;
  const int wave = t >> 6, lane = t & 63;
  const int lr = lane & 15, quad = lane >> 4;
  const int wm = (wave >> 1) * (BM / 2), wn = (wave & 1) * 64;

  auto stage = [&](int kt) {
    if constexpr (ABF16) {
      const u16* Ab = (const u16*)args.A[z];
      constexpr int NI = BM / 16;  // 1KB wave-instrs for the A tile
#pragma unroll
      for (int j = 0; j < (NI + 3) / 4; j++) {
        const int ii = wave + j * 4;
        if (NI >= 4 || ii < NI) {  // wave-uniform guard
          const int r0 = ii * 16;
          const int row = r0 + (lane >> 2);
          const int cg = (lane & 3) ^ ((lane >> 2) & 3);
          gl2lds16(Ab + (size_t)(m0 + row) * K + kt + cg * 8, AsB + r0 * 64 + lane * 16);
        }
      }
    } else {
      const float* Af = (const float*)args.A[z];
#pragma unroll
      for (int j = 0; j < BM / 32; j++) {
        const int r0 = wave * (BM / 4) + j * 8;
        const int row = r0 + (lane >> 3);
        const int cg = (lane & 7) ^ ((lane >> 3) & 7);
        gl2lds16(Af + (size_t)(m0 + row) * K + kt + cg * 4, AsB + r0 * 128 + lane * 16);
      }
    }
    if constexpr (WBF16) {
      const u16* Wb = (const u16*)args.W[z];
#pragma unroll
      for (int j = 0; j < 2; j++) {
        const int r0 = (wave + j * 4) * 16;
        const int row = r0 + (lane >> 2);
        const int cg = (lane & 3) ^ ((lane >> 2) & 3);
        gl2lds16(Wb + (size_t)(n0 + row) * K + kt + cg * 8, BsB + r0 * 64 + lane * 16);
      }
    } else {
      const float* Wf = (const float*)args.W[z];
#pragma unroll
      for (int j = 0; j < 4; j++) {
        const int r0 = wave * 32 + j * 8;
        const int row = r0 + (lane >> 3);
        const int cg = (lane & 7) ^ ((lane >> 3) & 7);
        gl2lds16(Wf + (size_t)(n0 + row) * K + kt + cg * 4, BsB + r0 * 128 + lane * 16);
      }
    }
  };

  floatx4 acc[MI][4] = {};

  for (int kt = 0; kt < K; kt += 32) {
    __syncthreads();  // prev-iter LDS reads done before overwrite
    stage(kt);
    __syncthreads();  // drains vmcnt(0): tile staged

    bf16x8 af[MI], bf[4];
#pragma unroll
    for (int i = 0; i < MI; i++) {
      const int row = wm + i * 16 + lr;
      if constexpr (ABF16) {
        const int cp = quad ^ (row & 3);
        af[i] = *reinterpret_cast<const bf16x8*>(AsB + row * 64 + cp * 16);
      } else {
        const int e = row & 7;
        const float4 c0 = *reinterpret_cast<const float4*>(AsB + row * 128 + ((2 * quad) ^ e) * 16);
        const float4 c1 = *reinterpret_cast<const float4*>(AsB + row * 128 + ((2 * quad + 1) ^ e) * 16);
        af[i] = cvt8(c0, c1);
      }
    }
#pragma unroll
    for (int i = 0; i < 4; i++) {
      const int row = wn + i * 16 + lr;
      if constexpr (WBF16) {
        const int cp = quad ^ (row & 3);
        bf[i] = *reinterpret_cast<const bf16x8*>(BsB + row * 64 + cp * 16);
      } else {
        const int e = row & 7;
        const float4 c0 = *reinterpret_cast<const float4*>(BsB + row * 128 + ((2 * quad) ^ e) * 16);
        const float4 c1 = *reinterpret_cast<const float4*>(BsB + row * 128 + ((2 * quad + 1) ^ e) * 16);
        bf[i] = cvt8(c0, c1);
      }
    }
#pragma unroll
    for (int mi = 0; mi < MI; mi++)
#pragma unroll
      for (int nf = 0; nf < 4; nf++)
        acc[mi][nf] = MFMA16(af[mi], bf[nf], acc[mi][nf]);
  }

  // epilogue: C-frag col = lane&15, row = quad*4 + reg
#pragma unroll
  for (int nf = 0; nf < 4; nf++) {
    const int col = n0 + wn + nf * 16 + lr;
    const float bv = bias[col];
#pragma unroll
    for (int mi = 0; mi < MI; mi++) {
      const int row0 = m0 + wm + mi * 16 + quad * 4;
      if (out_mode == 0) {
        u16* C = (u16*)args.C[z];
#pragma unroll
        for (int r = 0; r < 4; r++)
          C[(row0 + r) * N + col] = f2bf(acc[mi][nf][r] + bv);
      } else if (out_mode == 1) {
        u16* C = (u16*)args.C[z];
        const int h = col >> 6, d = col & 63;
        const int b = row0 >> 11, s = row0 & 2047;
        ushort4 pk;
        pk.x = f2bf(acc[mi][nf][0] + bv);
        pk.y = f2bf(acc[mi][nf][1] + bv);
        pk.z = f2bf(acc[mi][nf][2] + bv);
        pk.w = f2bf(acc[mi][nf][3] + bv);
        *reinterpret_cast<ushort4*>(&C[((b * 16 + h) * 64 + d) * 2048 + s]) = pk;
      } else {
        float* C = (float*)args.C[z];
#pragma unroll
        for (int r = 0; r < 4; r++)
          C[(row0 + r) * N + col] = acc[mi][nf][r] + bv;
      }
    }
  }
}

// Interleaved RoPE on K in-place (bf16). Q-rope is fused into attn_kernel
// (in-register, with the 0.125*log2e scale fold).
__global__ __launch_bounds__(256) void rope_kernel(u16* Kb) {
  const int idx = blockIdx.x * 256 + threadIdx.x;  // 524288 threads
  const int row = idx >> 7;
  const int cg = idx & 127;
  const int s = row & 2047;
  const int col0 = cg * 8;
  union { uint4 u; u16 h[8]; } v;
  v.u = *reinterpret_cast<const uint4*>(&Kb[row * 1024 + col0]);
  const int j0 = (col0 & 63) >> 1;
#pragma unroll
  for (int p = 0; p < 4; p++) {
    const int j = j0 + p;
    const float inv = exp2f(-(float)j * (13.287712379549449f / 32.0f));  // 10000^(-j/32)
    const float f = (float)s * inv;
    float sn, cs;
    sincosf(f, &sn, &cs);
    const float e = bf2f(v.h[2 * p]), o = bf2f(v.h[2 * p + 1]);
    v.h[2 * p]     = f2bf(e * cs - o * sn);
    v.h[2 * p + 1] = f2bf(o * cs + e * sn);
  }
  *reinterpret_cast<uint4*>(&Kb[row * 1024 + col0]) = v.u;
}

// P^T fragment build: regs g..g+7 of a 32-reg S^T acc hold
// k = base + (r&3) + 8*(r>>2) + 4*hi (hi = lane>>5), q = lane&31.
// B-operand of mfma32 needs lane to hold k = base + 8*hi + j (j=0..7).
// cvt_pk pairs + v_permlane32_swap_b32 (dst' = [dst.lo, src.lo],
// src' = [dst.hi, src.hi]; partner lane l^32 has the SAME q) produce exactly
// that: wA'=j{0,1}, wC'=j{2,3}, wB'=j{4,5}, wD'=j{6,7}.
#define MAKE_PB(pp, g, out) do {                                              \
    unsigned int wA, wB, wC, wD;                                              \
    asm("v_cvt_pk_bf16_f32 %0, %1, %2" : "=v"(wA) : "v"((pp)[(g)+0]), "v"((pp)[(g)+1])); \
    asm("v_cvt_pk_bf16_f32 %0, %1, %2" : "=v"(wB) : "v"((pp)[(g)+4]), "v"((pp)[(g)+5])); \
    asm("v_cvt_pk_bf16_f32 %0, %1, %2" : "=v"(wC) : "v"((pp)[(g)+2]), "v"((pp)[(g)+3])); \
    asm("v_cvt_pk_bf16_f32 %0, %1, %2" : "=v"(wD) : "v"((pp)[(g)+6]), "v"((pp)[(g)+7])); \
    asm("v_permlane32_swap_b32 %0, %1" : "+v"(wA), "+v"(wB));                 \
    asm("v_permlane32_swap_b32 %0, %1" : "+v"(wC), "+v"(wD));                 \
    union { unsigned int w[4]; bf16x8 v; } u_;                                \
    u_.w[0] = wA; u_.w[1] = wC; u_.w[2] = wB; u_.w[3] = wD;                   \
    (out) = u_.v;                                                             \
  } while (0)

// Flash attention v8 (R9 post-mortem): R9's 4-slot/2-tile schedule + setprio
// REGRESSED attn 57->78 us (MfmaUtil 23->17.5; more serialized). This is the
// R8-proven v6 loop body EXACTLY (2-slot, 1 tile/barrier, no setprio,
// measured 57.2 us), keeping only R9's fused Q-RoPE prologue (estimated
// ~0.4 us; if attn stays ~78 this bisects the culprit to the fusion).
__global__ __launch_bounds__(256, 2) void attn_kernel(const u16* Q, const u16* K,
                                                      const u16* Vt, u16* O) {
  // grid (16,32) = 512 blocks; chunk = 64/XCD -> 4 consecutive bh per XCD.
  const int lin = blockIdx.x + (blockIdx.y << 4);
  const int nid = (lin & 7) * 64 + (lin >> 3);
  const int bx = nid & 15, bh = nid >> 4;

  const int b = bh >> 4, h = bh & 15;
  const int t = threadIdx.x;
  const int warp = t >> 6, lane = t & 63;
  const int lq = lane & 31, hi = lane >> 5;

  __shared__ __align__(16) u16 Ks[2][64][64];
  __shared__ __align__(16) u16 Vs[2][64][64];

  const int q0 = bx * 128 + warp * 32;

  // Q B-frag: qf[s][j] = Q[q0+lq][h*64 + 16s + 8hi + j]
  const u16* qp = &Q[(size_t)(b * 2048 + q0 + lq) * 1024 + h * 64 + hi * 8];
  bf16x8 qf[4];
#pragma unroll
  for (int s = 0; s < 4; s++) qf[s] = *reinterpret_cast<const bf16x8*>(&qp[s * 16]);

  // In-register RoPE on Q + scale fold (0.125 * log2e). d = 16s+8hi+j;
  // pair p covers d = {16s+8hi+2p, +1} -> pair index jp = 8s+4hi+p.
  {
    const float seqf = (float)(q0 + lq);
#pragma unroll
    for (int s = 0; s < 4; s++) {
#pragma unroll
      for (int p = 0; p < 4; p++) {
        const int jp = s * 8 + hi * 4 + p;
        const float inv = exp2f(-(float)jp * (13.287712379549449f / 32.0f));
        float sn, cs;
        sincosf(seqf * inv, &sn, &cs);
        const float e = (float)qf[s][2 * p], o = (float)qf[s][2 * p + 1];
        qf[s][2 * p]     = (__bf16)((e * cs - o * sn) * 0.18033688011112042f);
        qf[s][2 * p + 1] = (__bf16)((o * cs + e * sn) * 0.18033688011112042f);
      }
    }
  }

  const u16* kbase = &K[(size_t)b * 2048 * 1024 + h * 64];
  const u16* vbase = &Vt[(size_t)bh * 131072];

  // Staging: lane l writes LDS granule (l&7) of row base+(l>>3); source
  // granule pre-swizzled (l&7)^(l>>3) => LDS granule g of row r holds
  // logical granule g^(r&7). Each warp stages 16 K-rows + 16 V-rows.
  const int srr = lane >> 3;            // 0..7 == dest row & 7
  const int scg = (lane & 7) ^ srr;     // swizzled source granule

  auto stage = [&](int kt2, int bufi) {
#pragma unroll
    for (int j = 0; j < 2; j++) {
      const int r0 = warp * 16 + j * 8;
      const int row = r0 + srr;
      gl2lds16(kbase + (size_t)(kt2 + row) * 1024 + scg * 8, &Ks[bufi][r0][0]);
      gl2lds16(vbase + (size_t)row * 2048 + kt2 + scg * 8, &Vs[bufi][r0][0]);
    }
  };

  floatx16 o0 = {}, o1 = {};
  float m = -1.0e30f, l = 0.0f;

  stage(0, 0);
  int buf = 0;
  for (int kt = 0; kt < 2048; kt += 64) {
    __syncthreads();  // drains vmcnt(0): stage(cur) done; prev-buf reads done
    if (kt + 64 < 2048) stage(kt + 64, buf ^ 1);  // async prefetch overlaps compute

    // K A-frag: kf[kb][s][j] = K[kt+32kb+lq][h*64+16s+8hi+j]
    bf16x8 kf[2][4], vf[4][2];
#pragma unroll
    for (int kb = 0; kb < 2; kb++) {
      const int r = kb * 32 + lq;
#pragma unroll
      for (int s = 0; s < 4; s++)
        kf[kb][s] = *reinterpret_cast<const bf16x8*>(&Ks[buf][r][((s * 2 + hi) ^ (r & 7)) * 8]);
    }
    // Vt A-frag: vf[ks][d][j] = Vt[32d+lq][kt+16ks+8hi+j]
#pragma unroll
    for (int d = 0; d < 2; d++) {
      const int r = d * 32 + lq;
#pragma unroll
      for (int ks = 0; ks < 4; ks++)
        vf[ks][d] = *reinterpret_cast<const bf16x8*>(&Vs[buf][r][((ks * 2 + hi) ^ (r & 7)) * 8]);
    }

    // QK^T: p0/p1 reg r = S^T[k = kt + 32kb + (r&3)+8*(r>>2)+4hi][q0+lq]
    floatx16 p0 = {}, p1 = {};
#pragma unroll
    for (int s = 0; s < 4; s++) {
      p0 = MFMA32(kf[0][s], qf[s], p0);
      p1 = MFMA32(kf[1][s], qf[s], p1);
    }

    // online softmax (log2 domain), q = lq lane-local; partner l^32 has other 32 k
    float mx = p0[0];
#pragma unroll
    for (int r = 1; r < 16; r++) mx = fmaxf(mx, p0[r]);
#pragma unroll
    for (int r = 0; r < 16; r++) mx = fmaxf(mx, p1[r]);
    mx = fmaxf(mx, __shfl_xor(mx, 32, 64));
    if (!__all(mx <= m + 10.0f)) {  // defer-max: P bounded by 2^10
      const float mn = fmaxf(m, mx);
      const float al = __builtin_amdgcn_exp2f(m - mn);
      m = mn;
      l *= al;
#pragma unroll
      for (int r = 0; r < 16; r++) { o0[r] *= al; o1[r] *= al; }
    }
    float sum = 0.0f;
#pragma unroll
    for (int r = 0; r < 16; r++) { p0[r] = __builtin_amdgcn_exp2f(p0[r] - m); sum += p0[r]; }
#pragma unroll
    for (int r = 0; r < 16; r++) { p1[r] = __builtin_amdgcn_exp2f(p1[r] - m); sum += p1[r]; }
    l += sum + __shfl_xor(sum, 32, 64);

    // P^T -> bf16 B-frags (in-register)
    bf16x8 pb0, pb1, pb2, pb3;
    MAKE_PB(p0, 0, pb0);
    MAKE_PB(p0, 8, pb1);
    MAKE_PB(p1, 0, pb2);
    MAKE_PB(p1, 8, pb3);

    // PV: O^T += Vt @ P^T
    o0 = MFMA32(vf[0][0], pb0, o0);
    o1 = MFMA32(vf[0][1], pb0, o1);
    o0 = MFMA32(vf[1][0], pb1, o0);
    o1 = MFMA32(vf[1][1], pb1, o1);
    o0 = MFMA32(vf[2][0], pb2, o0);
    o1 = MFMA32(vf[2][1], pb2, o1);
    o0 = MFMA32(vf[3][0], pb3, o0);
    o1 = MFMA32(vf[3][1], pb3, o1);

    buf ^= 1;
  }

  // epilogue: O^T reg r -> d = (r&3) + 8*(r>>2) + 4hi + 32*dblk, q = q0+lq
  const float rl = 1.0f / l;
  u16* op = &O[(size_t)(b * 2048 + q0 + lq) * 1024 + h * 64 + hi * 4];
#pragma unroll
  for (int rq = 0; rq < 4; rq++) {
    ushort4 s0, s1;
    s0.x = f2bf(o0[4 * rq + 0] * rl); s0.y = f2bf(o0[4 * rq + 1] * rl);
    s0.z = f2bf(o0[4 * rq + 2] * rl); s0.w = f2bf(o0[4 * rq + 3] * rl);
    s1.x = f2bf(o1[4 * rq + 0] * rl); s1.y = f2bf(o1[4 * rq + 1] * rl);
    s1.z = f2bf(o1[4 * rq + 2] * rl); s1.w = f2bf(o1[4 * rq + 3] * rl);
    *reinterpret_cast<ushort4*>(&op[rq * 8]) = s0;
    *reinterpret_cast<ushort4*>(&op[rq * 8 + 32]) = s1;
  }
}

extern "C" void kernel_launch(void* const* d_in, const int* in_sizes, int n_in,
                              void* d_out, int out_size, void* d_ws, size_t ws_size,
                              hipStream_t stream) {
  (void)in_sizes; (void)n_in; (void)out_size;
  const float* query = (const float*)d_in[0];
  const float* key   = (const float*)d_in[1];
  const float* value = (const float*)d_in[2];
  const float* Wq = (const float*)d_in[3];
  const float* bq = (const float*)d_in[4];
  const float* Wk = (const float*)d_in[5];
  const float* bk = (const float*)d_in[6];
  const float* Wv = (const float*)d_in[7];
  const float* bv = (const float*)d_in[8];
  const float* Wo = (const float*)d_in[9];
  const float* bo = (const float*)d_in[10];

  // Workspace: Qb [0, 8.4 MB) | Wbf 4x2 MB | Abf 3x8.4 MB.
  // Kb + Vt (16 MB bf16) live inside d_out (dead until final fp32 GEMM).
  u16* Qb = (u16*)d_ws;
  u16* Kb = (u16*)d_out;
  u16* Vt = (u16*)d_out + 4194304;

  const bool haveW = ws_size >= (size_t)(8388608 + 4 * 2097152);            // Qb + 4 W's
  const bool haveA = ws_size >= (size_t)(8388608 + 4 * 2097152 + 25165824); // + 3 A's
  u16* Wbf = (u16*)d_ws + 4194304;             // 4 x 1M u16
  u16* Abf = (u16*)d_ws + 4194304 + 4194304;   // 3 x 4M u16

  if (haveW) {
    CvtArgs cw;
    cw.src[0] = Wq; cw.dst[0] = Wbf;
    cw.src[1] = Wk; cw.dst[1] = Wbf + 1048576;
    cw.src[2] = Wv; cw.dst[2] = Wbf + 2097152;
    cw.src[3] = Wo; cw.dst[3] = Wbf + 3145728;
    cvt_kernel<<<dim3(512, 1, 4), dim3(256), 0, stream>>>(cw);
  }
  if (haveA) {
    CvtArgs ca;
    ca.src[0] = query; ca.dst[0] = Abf;
    ca.src[1] = key;   ca.dst[1] = Abf + 4194304;
    ca.src[2] = value; ca.dst[2] = Abf + 8388608;
    ca.src[3] = query; ca.dst[3] = Abf;  // unused (grid.z = 3)
    cvt_kernel<<<dim3(2048, 1, 3), dim3(256), 0, stream>>>(ca);
  }

  GemmArgs g1;
  g1.bias[0] = bq; g1.C[0] = Qb; g1.out_mode[0] = 0;
  g1.bias[1] = bk; g1.C[1] = Kb; g1.out_mode[1] = 0;
  g1.bias[2] = bv; g1.C[2] = Vt; g1.out_mode[2] = 1;
  if (haveA) {
    g1.A[0] = Abf; g1.A[1] = Abf + 4194304; g1.A[2] = Abf + 8388608;
  } else {
    g1.A[0] = query; g1.A[1] = key; g1.A[2] = value;
  }
  if (haveW) {
    g1.W[0] = Wbf; g1.W[1] = Wbf + 1048576; g1.W[2] = Wbf + 2097152;
  } else {
    g1.W[0] = Wq; g1.W[1] = Wk; g1.W[2] = Wv;
  }
  // BM=128 -> grid (8,32,3) = 768 blocks, single-buffer 2-barrier (R5-proven).
  if (haveA && haveW)
    gemm_nt<128, 1, 1><<<dim3(8, 32, 3), dim3(256), 0, stream>>>(g1);
  else if (haveW)
    gemm_nt<128, 0, 1><<<dim3(8, 32, 3), dim3(256), 0, stream>>>(g1);
  else
    gemm_nt<128, 0, 0><<<dim3(8, 32, 3), dim3(256), 0, stream>>>(g1);

  // K-only RoPE (Q-rope fused into attn).
  rope_kernel<<<dim3(2048), dim3(256), 0, stream>>>(Kb);

  attn_kernel<<<dim3(16, 32), dim3(256), 0, stream>>>(Qb, Kb, Vt, Qb);

  // Final projection: bf16 attn output -> fp32 d_out. BM=64 -> 512 blocks.
  GemmArgs g2;
  for (int i = 0; i < 3; i++) {
    g2.A[i] = Qb; g2.bias[i] = bo;
    g2.C[i] = d_out; g2.out_mode[i] = 2;
    g2.W[i] = haveW ? (const void*)(Wbf + 3145728) : (const void*)Wo;
  }
  if (haveW)
    gemm_nt<64, 1, 1><<<dim3(8, 64, 1), dim3(256), 0, stream>>>(g2);
  else
    gemm_nt<64, 1, 0><<<dim3(8, 64, 1), dim3(256), 0, stream>>>(g2);
}